// Round 12
// baseline (613.219 us; speedup 1.0000x reference)
//
#include <hip/hip_runtime.h>
#include <hip/hip_bf16.h>
#include <math.h>

// Problem constants
constexpr int Bc = 4;
constexpr int Sc = 2048;
constexpr int Dc = 512;
constexpr int Hc = 8;
constexpr int DHc = 64;
constexpr int Lc = 4;
constexpr int DFFc = 2048;
constexpr int Tc = Bc * Sc;   // 8192 tokens
constexpr int QKVW = 3 * Dc;  // 1536

typedef __attribute__((ext_vector_type(8))) short short8;
typedef __attribute__((ext_vector_type(4))) float f32x4;
typedef __attribute__((ext_vector_type(4))) float float4v;
typedef __attribute__((ext_vector_type(2))) float float2v;
typedef __attribute__((ext_vector_type(4))) unsigned int uint4v;
typedef __attribute__((ext_vector_type(2))) unsigned int uint2v;

static __device__ __forceinline__ float u16tof(unsigned int u) {
  return __uint_as_float(u << 16);
}
static __device__ __forceinline__ unsigned short ftobf(float f) {
  __hip_bfloat16 h = __float2bfloat16(f);
  return *reinterpret_cast<unsigned short*>(&h);
}
static __device__ __forceinline__ void gload_lds16(const void* g, void* l) {
  __builtin_amdgcn_global_load_lds(
      (const __attribute__((address_space(1))) void*)g,
      (__attribute__((address_space(3))) void*)l, 16, 0, 0);
}

// LDS chunk-swizzle helpers for attention (16B-chunk XOR, conflict-free b128)
static __device__ __forceinline__ int swzK(int row, int col) {  // width 64
  return row * 64 + ((((col >> 3) ^ (row & 7)) << 3) | (col & 7));
}
static __device__ __forceinline__ int swzW(int row, int col) {  // width 192
  return row * 192 + ((((col >> 3) ^ (row & 7)) << 3) | (col & 7));
}
// GEMM-family granule permutation: granule (row,ch), ch in [0,4), lives at
// linear slot p = (row>>1)*8 + ((((row&1)<<2)|ch) ^ ((row>>1)&7))
static __device__ __forceinline__ int gperm(int row, int ch) {
  return (row >> 1) * 8 + (((((row & 1) << 2) | ch)) ^ ((row >> 1) & 7));
}

// ---------------------------------------------------------------------------
// fp32 -> bf16 conversion (weights, once per launch)
// ---------------------------------------------------------------------------
__global__ __launch_bounds__(256) void k_f2bf(const float* __restrict__ in,
                                              unsigned short* __restrict__ out,
                                              int n) {
  int i = blockIdx.x * 256 + threadIdx.x;
  if (i < n) out[i] = ftobf(in[i]);
}

// ---------------------------------------------------------------------------
// Embed (vectorized x4): h = x @ W_in^T + b_in + pos ; also bf16 copy
// ---------------------------------------------------------------------------
__global__ __launch_bounds__(256) void k_embed(const float* __restrict__ x,
                                               const float* __restrict__ W_in,
                                               const float* __restrict__ b_in,
                                               const float* __restrict__ pos,
                                               float* __restrict__ h,
                                               unsigned short* __restrict__ hb) {
  int i4 = (blockIdx.x * 256 + threadIdx.x) * 4;
  int t = i4 >> 9;
  int d = i4 & 511;
  int s = t & (Sc - 1);
  float x0 = x[t * 2 + 0], x1 = x[t * 2 + 1];
  float4v w01 = *(const float4v*)&W_in[d * 2];        // {w[d].0,w[d].1,w[d+1].0,w[d+1].1}
  float4v w23 = *(const float4v*)&W_in[d * 2 + 4];
  float4v pz = *(const float4v*)&pos[(size_t)s * Dc + d];
  float4v b4 = *(const float4v*)&b_in[d];
  float4v v;
  v[0] = x0 * w01[0] + x1 * w01[1] + b4[0] + pz[0];
  v[1] = x0 * w01[2] + x1 * w01[3] + b4[1] + pz[1];
  v[2] = x0 * w23[0] + x1 * w23[1] + b4[2] + pz[2];
  v[3] = x0 * w23[2] + x1 * w23[3] + b4[3] + pz[3];
  *(float4v*)&h[i4] = v;
  uint2v pk = {ftobf(v[0]) | ((unsigned int)ftobf(v[1]) << 16),
               ftobf(v[2]) | ((unsigned int)ftobf(v[3]) << 16)};
  *(uint2v*)&hb[i4] = pk;
}

// ---------------------------------------------------------------------------
// MFMA bf16 GEMM: 128x128 tile, BK=32, 2-buffer, 4 waves (2x2), chunk-XOR
// swizzled LDS (0 conflicts in K-loop), XCD block swizzle, (256,4).
// LDS-transpose epilogue: coalesced dwordx4 stores.
//   MODE 0: +bias ; MODE 2: +bias, exact GELU
//   OUTBF: 1 -> bf16 out, 0 -> fp32 out
// ---------------------------------------------------------------------------
template <int MODE, int OUTBF>
__global__ __launch_bounds__(256, 4) void k_mgemm(const unsigned short* __restrict__ A,
                                                  const unsigned short* __restrict__ W,
                                                  const float* __restrict__ bias,
                                                  void* __restrict__ Cout,
                                                  int M, int N, int K) {
  __shared__ short SMEM[2][2][512 * 8];
  const int tid = threadIdx.x;
  const int lane = tid & 63;
  const int wid = tid >> 6;
  const int wm = wid >> 1;
  const int wn = wid & 1;

  const int nwg = gridDim.x * gridDim.y;
  const int bid = blockIdx.y * gridDim.x + blockIdx.x;
  const int swz = (bid & 7) * (nwg >> 3) + (bid >> 3);
  const int m0 = (swz / gridDim.x) * 128;
  const int n0 = (swz % gridDim.x) * 128;

  int r0S, c0S, r1S, c1S;
  {
    int p = tid;
    int rp = p >> 3, q = (p & 7) ^ (rp & 7);
    r0S = (rp << 1) | (q >> 2);
    c0S = q & 3;
    p = tid + 256;
    rp = p >> 3;
    q = (p & 7) ^ (rp & 7);
    r1S = (rp << 1) | (q >> 2);
    c1S = q & 3;
  }
  const unsigned short* a0p = A + (size_t)(m0 + r0S) * K + c0S * 8;
  const unsigned short* a1p = A + (size_t)(m0 + r1S) * K + c1S * 8;
  const unsigned short* b0p = W + (size_t)(n0 + r0S) * K + c0S * 8;
  const unsigned short* b1p = W + (size_t)(n0 + r1S) * K + c1S * 8;
  const int d0 = (tid & ~63) * 8;
  const int d1 = ((tid + 256) & ~63) * 8;

  f32x4 acc[4][4] = {};
  const int lr = lane & 15;
  const int chr = lane >> 4;

  gload_lds16(a0p, &SMEM[0][0][d0]);
  gload_lds16(a1p, &SMEM[0][0][d1]);
  gload_lds16(b0p, &SMEM[1][0][d0]);
  gload_lds16(b1p, &SMEM[1][0][d1]);
  __syncthreads();

  const int nsteps = K >> 5;
  int buf = 0;
  for (int s = 0; s < nsteps; ++s) {
    if (s + 1 < nsteps) {
      const int ko = (s + 1) << 5;
      gload_lds16(a0p + ko, &SMEM[0][buf ^ 1][d0]);
      gload_lds16(a1p + ko, &SMEM[0][buf ^ 1][d1]);
      gload_lds16(b0p + ko, &SMEM[1][buf ^ 1][d0]);
      gload_lds16(b1p + ko, &SMEM[1][buf ^ 1][d1]);
    }
    short8 af[4], bfr[4];
#pragma unroll
    for (int mi = 0; mi < 4; ++mi)
      af[mi] = *(const short8*)&SMEM[0][buf][gperm(wm * 64 + mi * 16 + lr, chr) * 8];
#pragma unroll
    for (int ni = 0; ni < 4; ++ni)
      bfr[ni] = *(const short8*)&SMEM[1][buf][gperm(wn * 64 + ni * 16 + lr, chr) * 8];
#pragma unroll
    for (int mi = 0; mi < 4; ++mi)
#pragma unroll
      for (int ni = 0; ni < 4; ++ni)
        acc[mi][ni] = __builtin_amdgcn_mfma_f32_16x16x32_bf16(
            af[mi], bfr[ni], acc[mi][ni], 0, 0, 0);
    __syncthreads();
    buf ^= 1;
  }

  // LDS-transpose epilogue
  float* cw = (float*)&SMEM[0][0][0] + wid * (16 * 68);
  const int cj = lane & 15;
  const int rj4 = (lane >> 4) * 4;
  const int rrd = lane >> 3;
  const int crd = (lane & 7) * 8;
#pragma unroll
  for (int mi = 0; mi < 4; ++mi) {
#pragma unroll
    for (int ni = 0; ni < 4; ++ni) {
      float bn = bias[n0 + wn * 64 + ni * 16 + cj];
#pragma unroll
      for (int j = 0; j < 4; ++j) {
        float v = acc[mi][ni][j] + bn;
        if (MODE == 2) v = 0.5f * v * (1.0f + erff(v * 0.70710678118654752f));
        cw[(rj4 + j) * 68 + ni * 16 + cj] = v;
      }
    }
    __builtin_amdgcn_sched_barrier(0);
#pragma unroll
    for (int t = 0; t < 2; ++t) {
      int rl = t * 8 + rrd;
      float4v v0 = *(const float4v*)&cw[rl * 68 + crd];
      float4v v1 = *(const float4v*)&cw[rl * 68 + crd + 4];
      size_t gbase = (size_t)(m0 + wm * 64 + mi * 16 + rl) * N +
                     (n0 + wn * 64 + crd);
      if (OUTBF) {
        unsigned int w0 = ftobf(v0[0]) | ((unsigned int)ftobf(v0[1]) << 16);
        unsigned int w1 = ftobf(v0[2]) | ((unsigned int)ftobf(v0[3]) << 16);
        unsigned int w2 = ftobf(v1[0]) | ((unsigned int)ftobf(v1[1]) << 16);
        unsigned int w3 = ftobf(v1[2]) | ((unsigned int)ftobf(v1[3]) << 16);
        uint4v pk = {w0, w1, w2, w3};
        *(uint4v*)&((unsigned short*)Cout)[gbase] = pk;
      } else {
        *(float4v*)&((float*)Cout)[gbase] = v0;
        *(float4v*)&((float*)Cout)[gbase + 4] = v1;
      }
    }
    __builtin_amdgcn_sched_barrier(0);
  }
}

// ---------------------------------------------------------------------------
// k_gln: fused GEMM(16xN512,K=KK) + bias + residual + LayerNorm.
//   h = LN(h + A@W^T + bias); writes h fp32 and hb bf16.
// 256 thr, 4 waves; wave wn owns cols wn*128..+128 of all 16 rows.
// B (512xBK) staged via inverse-permuted gload_lds (W is L2-resident);
// A (16xBK) staged by wave 0 via reg-prefetched ds_write (no rule-21 limit).
// Epilogue: acc+bias -> LDS f32 [16][512]; per-row full-wave reduce -> LN.
// ---------------------------------------------------------------------------
template <int KK>
__global__ __launch_bounds__(256, 2) void k_gln(const unsigned short* __restrict__ A,
                                                const unsigned short* __restrict__ W,
                                                const float* __restrict__ bias,
                                                const float* __restrict__ g,
                                                const float* __restrict__ bta,
                                                float* __restrict__ h,
                                                unsigned short* __restrict__ hb) {
  constexpr int NSTEP = KK / 32;
  __shared__ unsigned short Bs[2][512 * 32];  // 64 KB
  __shared__ unsigned short As[2][16 * 32];   // 2 KB
  const int tid = threadIdx.x;
  const int lane = tid & 63;
  const int w = tid >> 6;  // wave id = N-quarter

  // XCD swizzle (grid 512, %8==0)
  const int nwg = gridDim.x;
  const int bid = blockIdx.x;
  const int swz = (bid & 7) * (nwg >> 3) + (bid >> 3);
  const int m0 = swz * 16;

  // B staging geometry: 2048 granules, 8 instrs x 256 thr; inverse permute.
  const unsigned short* WpS[8];
  int dstB[8];
#pragma unroll
  for (int i = 0; i < 8; ++i) {
    int p = i * 256 + tid;
    int rp = p >> 3, q = (p & 7) ^ (rp & 7);
    int row = (rp << 1) | (q >> 2);
    int ch = q & 3;
    WpS[i] = W + (size_t)row * KK + ch * 8;
    dstB[i] = ((i * 256 + tid) & ~63) * 8;  // shorts
  }
  // A staging: wave 0, thread t<64: granule (row=t>>2, ch=t&3)
  const int arow = tid >> 2, ach = tid & 3;
  const unsigned short* ApS = A + (size_t)(m0 + arow) * KK + ach * 8;
  const int apos = gperm(arow, ach) * 8;

  f32x4 acc[8] = {};
  const int lr = lane & 15;
  const int chr = lane >> 4;

  // prologue
#pragma unroll
  for (int i = 0; i < 8; ++i) gload_lds16(WpS[i], &Bs[0][dstB[i]]);
  short8 aval = {};
  if (tid < 64) {
    aval = *(const short8*)ApS;
    *(short8*)&As[0][apos] = aval;            // waits vmcnt once (prologue only)
    if (NSTEP > 1) aval = *(const short8*)(ApS + 32);
  }
  __syncthreads();

  int buf = 0;
  for (int s = 0; s < NSTEP; ++s) {
    if (s + 1 < NSTEP) {
      const int ko = (s + 1) << 5;
#pragma unroll
      for (int i = 0; i < 8; ++i) gload_lds16(WpS[i] + ko, &Bs[buf ^ 1][dstB[i]]);
      if (tid < 64) {
        *(short8*)&As[buf ^ 1][apos] = aval;  // value prefetched last step
        if (s + 2 < NSTEP) aval = *(const short8*)(ApS + ((s + 2) << 5));
      }
    }
    short8 af = *(const short8*)&As[buf][gperm(lr, chr) * 8];
    short8 bfr[8];
#pragma unroll
    for (int ni = 0; ni < 8; ++ni)
      bfr[ni] = *(const short8*)&Bs[buf][gperm(w * 128 + ni * 16 + lr, chr) * 8];
#pragma unroll
    for (int ni = 0; ni < 8; ++ni)
      acc[ni] = __builtin_amdgcn_mfma_f32_16x16x32_bf16(af, bfr[ni], acc[ni], 0, 0, 0);
    __syncthreads();
    buf ^= 1;
  }

  // ---- fused epilogue: acc+bias -> LDS [16][512] f32, then per-row LN ----
  float* cw = (float*)&Bs[0][0];  // 32 KB scratch
  const int cj = lane & 15;
  const int rj4 = (lane >> 4) * 4;
#pragma unroll
  for (int ni = 0; ni < 8; ++ni) {
    int col = w * 128 + ni * 16 + cj;
    float bn = bias[col];
#pragma unroll
    for (int j = 0; j < 4; ++j)
      cw[(rj4 + j) * 512 + col] = acc[ni][j] + bn;
  }
  __syncthreads();

  // wave w handles rows w*4 .. w*4+3
#pragma unroll
  for (int r = 0; r < 4; ++r) {
    const int row = w * 4 + r;
    const size_t gm = (size_t)(m0 + row) * Dc;
    float4v x0 = *(const float4v*)&cw[row * 512 + lane * 8];
    float4v x1 = *(const float4v*)&cw[row * 512 + lane * 8 + 4];
    float4v h0 = *(const float4v*)&h[gm + lane * 8];
    float4v h1 = *(const float4v*)&h[gm + lane * 8 + 4];
    float v[8];
    float sum = 0.f, sq = 0.f;
#pragma unroll
    for (int c = 0; c < 4; ++c) {
      v[c] = x0[c] + h0[c];
      v[4 + c] = x1[c] + h1[c];
    }
#pragma unroll
    for (int c = 0; c < 8; ++c) {
      sum += v[c];
      sq += v[c] * v[c];
    }
#pragma unroll
    for (int off = 32; off; off >>= 1) {
      sum += __shfl_xor(sum, off);
      sq += __shfl_xor(sq, off);
    }
    float mu = sum * (1.0f / 512.0f);
    float var = sq * (1.0f / 512.0f) - mu * mu;
    float rstd = rsqrtf(var + 1e-5f);
    float4v o0, o1;
#pragma unroll
    for (int c = 0; c < 4; ++c) {
      o0[c] = (v[c] - mu) * rstd * g[lane * 8 + c] + bta[lane * 8 + c];
      o1[c] = (v[4 + c] - mu) * rstd * g[lane * 8 + 4 + c] + bta[lane * 8 + 4 + c];
    }
    *(float4v*)&h[gm + lane * 8] = o0;
    *(float4v*)&h[gm + lane * 8 + 4] = o1;
    uint4v pk = {ftobf(o0[0]) | ((unsigned int)ftobf(o0[1]) << 16),
                 ftobf(o0[2]) | ((unsigned int)ftobf(o0[3]) << 16),
                 ftobf(o1[0]) | ((unsigned int)ftobf(o1[1]) << 16),
                 ftobf(o1[2]) | ((unsigned int)ftobf(o1[3]) << 16)};
    *(uint4v*)&hb[gm + lane * 8] = pk;
  }
}

// ---------------------------------------------------------------------------
// Windowed causal attention, MFMA. qkv bf16 [T][1536]. PV kb-range trimmed.
// ---------------------------------------------------------------------------
__global__ __launch_bounds__(256, 3) void k_attn(const unsigned short* __restrict__ qkv,
                                                 unsigned short* __restrict__ o) {
  __shared__ unsigned short KPs[192 * 64];  // K rows, then reused as P
  __shared__ unsigned short Vt[64 * 192];

  const int tid = threadIdx.x;
  const int lane = tid & 63;
  const int w = tid >> 6;
  const int idx = blockIdx.x;
  const int qb = idx & 31;
  const int hh = (idx >> 5) & 7;
  const int b = idx >> 8;
  const int q0 = qb * 64;
  const int kstart = max(0, q0 - 128);
  const int nk = q0 + 64 - kstart;  // 64 (qb==0) or 192

  for (int c = tid; c < nk * 8; c += 256) {
    int j = c >> 3, ch = c & 7;
    short8 kv = *(const short8*)&qkv[(size_t)(b * Sc + kstart + j) * QKVW + Dc + hh * DHc + ch * 8];
    *(short8*)&KPs[swzK(j, ch * 8)] = kv;
  }
  for (int c = tid; c < (nk >> 1) * 8; c += 256) {
    int jp = c >> 3, ch = c & 7;
    int j = jp * 2;
    const unsigned short* base =
        &qkv[(size_t)(b * Sc + kstart + j) * QKVW + 2 * Dc + hh * DHc + ch * 8];
    short8 v0 = *(const short8*)base;
    short8 v1 = *(const short8*)(base + QKVW);
#pragma unroll
    for (int i = 0; i < 8; ++i) {
      unsigned int pk = (unsigned short)v0[i] | ((unsigned int)(unsigned short)v1[i] << 16);
      *(unsigned int*)&Vt[swzW(ch * 8 + i, j)] = pk;
    }
  }
  if (nk < 192) {
    for (int c = tid; c < 64 * 64; c += 256) {
      int d = c >> 6, jo = c & 63;
      *(unsigned int*)&Vt[swzW(d, 64 + jo * 2)] = 0;
    }
  }

  const int qg = q0 + w * 16 + (lane & 15);
  const int kg8 = (lane >> 4) * 8;
  const unsigned short* qp = &qkv[(size_t)(b * Sc + qg) * QKVW + hh * DHc + kg8];
  short8 bq0 = *(const short8*)qp;
  short8 bq1 = *(const short8*)(qp + 32);
  __syncthreads();

  const int jb = max(0, q0 + w * 16 - 128) - kstart;

  f32x4 sacc[9];
#pragma unroll
  for (int t = 0; t < 9; ++t) {
    int key = jb + t * 16 + (lane & 15);
    short8 a0 = *(const short8*)&KPs[swzK(key, kg8)];
    short8 a1 = *(const short8*)&KPs[swzK(key, 32 + kg8)];
    f32x4 z = {0.f, 0.f, 0.f, 0.f};
    z = __builtin_amdgcn_mfma_f32_16x16x32_bf16(a0, bq0, z, 0, 0, 0);
    sacc[t] = __builtin_amdgcn_mfma_f32_16x16x32_bf16(a1, bq1, z, 0, 0, 0);
  }

  const int rj = (lane >> 4) * 4;
  float mx = -1e30f;
#pragma unroll
  for (int t = 0; t < 9; ++t) {
#pragma unroll
    for (int j = 0; j < 4; ++j) {
      int kglob = kstart + jb + t * 16 + rj + j;
      bool valid = (kglob <= qg) && (kglob + 128 >= qg);
      float s = valid ? sacc[t][j] * 0.125f : -1e30f;
      sacc[t][j] = s;
      mx = fmaxf(mx, s);
    }
  }
  mx = fmaxf(mx, __shfl_xor(mx, 16));
  mx = fmaxf(mx, __shfl_xor(mx, 32));
  float sum = 0.f;
#pragma unroll
  for (int t = 0; t < 9; ++t)
#pragma unroll
    for (int j = 0; j < 4; ++j) {
      float e = __expf(sacc[t][j] - mx);
      sacc[t][j] = e;
      sum += e;
    }
  sum += __shfl_xor(sum, 16);
  sum += __shfl_xor(sum, 32);
  const float inv = 1.0f / sum;

  // all K reads complete; hand KPs over to P storage
  __syncthreads();

  const int prow = w * 16 + (lane & 15);
#pragma unroll
  for (int t = 0; t < 9; ++t) {
    int c0 = jb + t * 16 + rj;
    unsigned int p0 = ftobf(sacc[t][0] * inv) |
                      ((unsigned int)ftobf(sacc[t][1] * inv) << 16);
    unsigned int p1 = ftobf(sacc[t][2] * inv) |
                      ((unsigned int)ftobf(sacc[t][3] * inv) << 16);
    *(unsigned int*)&KPs[swzW(prow, c0)] = p0;
    *(unsigned int*)&KPs[swzW(prow, c0 + 2)] = p1;
  }
  {
    int g2 = (lane >> 4) * 2;
    for (int col = g2; col < jb; col += 8)
      *(unsigned int*)&KPs[swzW(prow, col)] = 0;
    for (int col = jb + 144 + g2; col < 192; col += 8)
      *(unsigned int*)&KPs[swzW(prow, col)] = 0;
  }
  // PV over the wave's valid kb range only (always 5 of 6 iterations)
  const int kb0 = jb >> 5;
  const int kbend = min(6, (jb + 144 + 31) >> 5);
  f32x4 oacc[4] = {};
  for (int kb = kb0; kb < kbend; ++kb) {
    short8 pa = *(const short8*)&KPs[swzW(prow, kb * 32 + kg8)];
#pragma unroll
    for (int dt = 0; dt < 4; ++dt) {
      short8 vb = *(const short8*)&Vt[swzW(dt * 16 + (lane & 15), kb * 32 + kg8)];
      oacc[dt] = __builtin_amdgcn_mfma_f32_16x16x32_bf16(pa, vb, oacc[dt], 0, 0, 0);
    }
  }
  const int cj = lane & 15;
#pragma unroll
  for (int j = 0; j < 4; ++j)
#pragma unroll
    for (int dt = 0; dt < 4; ++dt)
      o[(size_t)(b * Sc + q0 + w * 16 + rj + j) * Dc + hh * DHc + dt * 16 + cj] =
          ftobf(oacc[dt][j]);
}

// ---------------------------------------------------------------------------
// Residual + LayerNorm (used after W2): h = LN(h + raw); h fp32 + hb bf16.
// ---------------------------------------------------------------------------
__global__ __launch_bounds__(256) void k_lnr(float* __restrict__ h,
                                             const float* __restrict__ raw,
                                             const float* __restrict__ g,
                                             const float* __restrict__ bta,
                                             unsigned short* __restrict__ outb) {
  const int wid = threadIdx.x >> 6;
  const int lane = threadIdx.x & 63;
  const int t = blockIdx.x * 4 + wid;
  const float4v* hrow = (const float4v*)(h + (size_t)t * Dc);
  const float4v* rrow = (const float4v*)(raw + (size_t)t * Dc);
  float4v v[2];
  float sum = 0.0f, sq = 0.0f;
#pragma unroll
  for (int i = 0; i < 2; ++i) {
    float4v hv = hrow[lane + i * 64];
    float4v rv = rrow[lane + i * 64];
#pragma unroll
    for (int c = 0; c < 4; ++c) {
      float xv = rv[c] + hv[c];
      v[i][c] = xv;
      sum += xv;
      sq += xv * xv;
    }
  }
#pragma unroll
  for (int off = 32; off; off >>= 1) {
    sum += __shfl_xor(sum, off);
    sq += __shfl_xor(sq, off);
  }
  float m = sum * (1.0f / 512.0f);
  float var = sq * (1.0f / 512.0f) - m * m;
  float rstd = rsqrtf(var + 1e-5f);
  float4v* orow = (float4v*)(h + (size_t)t * Dc);
  unsigned int* brow = (unsigned int*)(outb + (size_t)t * Dc);
#pragma unroll
  for (int i = 0; i < 2; ++i) {
    int d4 = (lane + i * 64) * 4;
    float4v ov;
#pragma unroll
    for (int c = 0; c < 4; ++c)
      ov[c] = (v[i][c] - m) * rstd * g[d4 + c] + bta[d4 + c];
    orow[lane + i * 64] = ov;
    unsigned int p0 = ftobf(ov[0]) | ((unsigned int)ftobf(ov[1]) << 16);
    unsigned int p1 = ftobf(ov[2]) | ((unsigned int)ftobf(ov[3]) << 16);
    brow[(lane + i * 64) * 2] = p0;
    brow[(lane + i * 64) * 2 + 1] = p1;
  }
}

// ---------------------------------------------------------------------------
// Head (fp32): mu | clipped log_sigma
// ---------------------------------------------------------------------------
__global__ __launch_bounds__(256) void k_head(const float* __restrict__ h,
                                              const float* __restrict__ Wh,
                                              const float* __restrict__ bh,
                                              float* __restrict__ outp) {
  const int wid = threadIdx.x >> 6;
  const int lane = threadIdx.x & 63;
  const int t = blockIdx.x * 4 + wid;
  const float* row = h + (size_t)t * Dc;
  float a0 = 0, a1 = 0, a2 = 0, a3 = 0;
#pragma unroll
  for (int i = 0; i < 8; ++i) {
    int d = lane + i * 64;
    float xv = row[d];
    a0 += xv * Wh[0 * Dc + d];
    a1 += xv * Wh[1 * Dc + d];
    a2 += xv * Wh[2 * Dc + d];
    a3 += xv * Wh[3 * Dc + d];
  }
#pragma unroll
  for (int off = 32; off; off >>= 1) {
    a0 += __shfl_xor(a0, off);
    a1 += __shfl_xor(a1, off);
    a2 += __shfl_xor(a2, off);
    a3 += __shfl_xor(a3, off);
  }
  if (lane == 0) {
    outp[(size_t)t * 2 + 0] = a0 + bh[0];
    outp[(size_t)t * 2 + 1] = a1 + bh[1];
    outp[(size_t)Tc * 2 + (size_t)t * 2 + 0] = fminf(fmaxf(a2 + bh[2], -6.0f), 1.5f);
    outp[(size_t)Tc * 2 + (size_t)t * 2 + 1] = fminf(fmaxf(a3 + bh[3], -6.0f), 1.5f);
  }
}

// ---------------------------------------------------------------------------
extern "C" void kernel_launch(void* const* d_in, const int* in_sizes, int n_in,
                              void* d_out, int out_size, void* d_ws, size_t ws_size,
                              hipStream_t stream) {
  const float* x    = (const float*)d_in[0];
  const float* W_in = (const float*)d_in[1];
  const float* b_in = (const float*)d_in[2];
  const float* pos  = (const float*)d_in[3];
  const float* Wqkv = (const float*)d_in[4];
  const float* bqkv = (const float*)d_in[5];
  const float* Wo   = (const float*)d_in[6];
  const float* bo   = (const float*)d_in[7];
  const float* W1   = (const float*)d_in[8];
  const float* b1   = (const float*)d_in[9];
  const float* W2   = (const float*)d_in[10];
  const float* b2   = (const float*)d_in[11];
  const float* ln1g = (const float*)d_in[12];
  const float* ln1b = (const float*)d_in[13];
  const float* ln2g = (const float*)d_in[14];
  const float* ln2b = (const float*)d_in[15];
  const float* Wh   = (const float*)d_in[16];
  const float* bh   = (const float*)d_in[17];
  float* out = (float*)d_out;

  char* p = (char*)d_ws;
  float* h   = (float*)p;          p += (size_t)Tc * Dc * 4;   // residual stream fp32
  float* t2  = (float*)p;          p += (size_t)Tc * Dc * 4;   // raw W2 out fp32
  unsigned short* hb  = (unsigned short*)p; p += (size_t)Tc * Dc * 2;
  unsigned short* ob  = (unsigned short*)p; p += (size_t)Tc * Dc * 2;
  unsigned short* big = (unsigned short*)p; p += (size_t)Tc * DFFc * 2;
  unsigned short* wqb = (unsigned short*)p; p += (size_t)Lc * QKVW * Dc * 2;
  unsigned short* wob = (unsigned short*)p; p += (size_t)Lc * Dc * Dc * 2;
  unsigned short* w1b = (unsigned short*)p; p += (size_t)Lc * DFFc * Dc * 2;
  unsigned short* w2b = (unsigned short*)p; p += (size_t)Lc * Dc * DFFc * 2;

  k_f2bf<<<Lc * QKVW * Dc / 256, 256, 0, stream>>>(Wqkv, wqb, Lc * QKVW * Dc);
  k_f2bf<<<Lc * Dc * Dc / 256, 256, 0, stream>>>(Wo, wob, Lc * Dc * Dc);
  k_f2bf<<<Lc * DFFc * Dc / 256, 256, 0, stream>>>(W1, w1b, Lc * DFFc * Dc);
  k_f2bf<<<Lc * Dc * DFFc / 256, 256, 0, stream>>>(W2, w2b, Lc * Dc * DFFc);

  k_embed<<<(Tc * Dc) / 1024, 256, 0, stream>>>(x, W_in, b_in, pos, h, hb);

  for (int l = 0; l < Lc; ++l) {
    const unsigned short* wq_l = wqb + (size_t)l * QKVW * Dc;
    const unsigned short* wo_l = wob + (size_t)l * Dc * Dc;
    const unsigned short* w1_l = w1b + (size_t)l * DFFc * Dc;
    const unsigned short* w2_l = w2b + (size_t)l * Dc * DFFc;

    // qkv = hb @ Wqkv^T + bqkv  (bf16 out)
    k_mgemm<0, 1><<<dim3(QKVW / 128, Tc / 128), 256, 0, stream>>>(
        hb, wq_l, bqkv + (size_t)l * QKVW, big, Tc, QKVW, Dc);

    k_attn<<<Bc * Hc * (Sc / 64), 256, 0, stream>>>(big, ob);

    // h = LN1(h + ob @ Wo^T + bo); hb = bf16(h)  [fused]
    k_gln<Dc><<<Tc / 16, 256, 0, stream>>>(
        ob, wo_l, bo + (size_t)l * Dc, ln1g + (size_t)l * Dc,
        ln1b + (size_t)l * Dc, h, hb);

    // big = gelu(hb @ W1^T + b1)  (bf16 out)
    k_mgemm<2, 1><<<dim3(DFFc / 128, Tc / 128), 256, 0, stream>>>(
        hb, w1_l, b1 + (size_t)l * DFFc, big, Tc, DFFc, Dc);

    // t2 = big @ W2^T + b2  (fp32 raw)
    k_mgemm<0, 0><<<dim3(Dc / 128, Tc / 128), 256, 0, stream>>>(
        big, w2_l, b2 + (size_t)l * Dc, t2, Tc, Dc, DFFc);

    // h = LN2(h + t2); hb = bf16(h)
    k_lnr<<<Tc / 4, 256, 0, stream>>>(h, t2, ln2g + (size_t)l * Dc,
                                      ln2b + (size_t)l * Dc, hb);
  }

  k_head<<<Tc / 4, 256, 0, stream>>>(h, Wh, bh, out);
}

// Round 13
// 592.375 us; speedup vs baseline: 1.0352x; 1.0352x over previous
//
#include <hip/hip_runtime.h>
#include <hip/hip_bf16.h>
#include <math.h>

// Problem constants
constexpr int Bc = 4;
constexpr int Sc = 2048;
constexpr int Dc = 512;
constexpr int Hc = 8;
constexpr int DHc = 64;
constexpr int Lc = 4;
constexpr int DFFc = 2048;
constexpr int Tc = Bc * Sc;   // 8192 tokens
constexpr int QKVW = 3 * Dc;  // 1536

typedef __attribute__((ext_vector_type(8))) short short8;
typedef __attribute__((ext_vector_type(4))) float f32x4;
typedef __attribute__((ext_vector_type(4))) float float4v;
typedef __attribute__((ext_vector_type(4))) unsigned int uint4v;
typedef __attribute__((ext_vector_type(2))) unsigned int uint2v;

static __device__ __forceinline__ float u16tof(unsigned int u) {
  return __uint_as_float(u << 16);
}
static __device__ __forceinline__ unsigned short ftobf(float f) {
  __hip_bfloat16 h = __float2bfloat16(f);
  return *reinterpret_cast<unsigned short*>(&h);
}
static __device__ __forceinline__ void gload_lds16(const void* g, void* l) {
  __builtin_amdgcn_global_load_lds(
      (const __attribute__((address_space(1))) void*)g,
      (__attribute__((address_space(3))) void*)l, 16, 0, 0);
}

// LDS chunk-swizzle helpers for attention (16B-chunk XOR, conflict-free b128)
static __device__ __forceinline__ int swzK(int row, int col) {  // width 64
  return row * 64 + ((((col >> 3) ^ (row & 7)) << 3) | (col & 7));
}
static __device__ __forceinline__ int swzW(int row, int col) {  // width 192
  return row * 192 + ((((col >> 3) ^ (row & 7)) << 3) | (col & 7));
}
// GEMM-family granule permutation
static __device__ __forceinline__ int gperm(int row, int ch) {
  return (row >> 1) * 8 + (((((row & 1) << 2) | ch)) ^ ((row >> 1) & 7));
}

// ---------------------------------------------------------------------------
// Merged fp32 -> bf16 weight conversion (all 4 tensors, one launch, x4 vec)
// ---------------------------------------------------------------------------
__global__ __launch_bounds__(256) void k_f2bf4(const float* __restrict__ p0,
                                               const float* __restrict__ p1,
                                               const float* __restrict__ p2,
                                               const float* __restrict__ p3,
                                               unsigned short* __restrict__ o0,
                                               unsigned short* __restrict__ o1,
                                               unsigned short* __restrict__ o2,
                                               unsigned short* __restrict__ o3,
                                               int n0, int n01, int n012, int n0123) {
  int i4 = (blockIdx.x * 256 + threadIdx.x) * 4;
  if (i4 >= n0123) return;
  const float* src;
  unsigned short* dst;
  int off;
  if (i4 < n0) { src = p0; dst = o0; off = i4; }
  else if (i4 < n01) { src = p1; dst = o1; off = i4 - n0; }
  else if (i4 < n012) { src = p2; dst = o2; off = i4 - n01; }
  else { src = p3; dst = o3; off = i4 - n012; }
  float4v v = *(const float4v*)&src[off];
  uint2v pk = {ftobf(v[0]) | ((unsigned int)ftobf(v[1]) << 16),
               ftobf(v[2]) | ((unsigned int)ftobf(v[3]) << 16)};
  *(uint2v*)&dst[off] = pk;
}

// ---------------------------------------------------------------------------
// Embed (vectorized x4): h = x @ W_in^T + b_in + pos ; also bf16 copy
// ---------------------------------------------------------------------------
__global__ __launch_bounds__(256) void k_embed(const float* __restrict__ x,
                                               const float* __restrict__ W_in,
                                               const float* __restrict__ b_in,
                                               const float* __restrict__ pos,
                                               float* __restrict__ h,
                                               unsigned short* __restrict__ hb) {
  int i4 = (blockIdx.x * 256 + threadIdx.x) * 4;
  int t = i4 >> 9;
  int d = i4 & 511;
  int s = t & (Sc - 1);
  float x0 = x[t * 2 + 0], x1 = x[t * 2 + 1];
  float4v w01 = *(const float4v*)&W_in[d * 2];
  float4v w23 = *(const float4v*)&W_in[d * 2 + 4];
  float4v pz = *(const float4v*)&pos[(size_t)s * Dc + d];
  float4v b4 = *(const float4v*)&b_in[d];
  float4v v;
  v[0] = x0 * w01[0] + x1 * w01[1] + b4[0] + pz[0];
  v[1] = x0 * w01[2] + x1 * w01[3] + b4[1] + pz[1];
  v[2] = x0 * w23[0] + x1 * w23[1] + b4[2] + pz[2];
  v[3] = x0 * w23[2] + x1 * w23[3] + b4[3] + pz[3];
  *(float4v*)&h[i4] = v;
  uint2v pk = {ftobf(v[0]) | ((unsigned int)ftobf(v[1]) << 16),
               ftobf(v[2]) | ((unsigned int)ftobf(v[3]) << 16)};
  *(uint2v*)&hb[i4] = pk;
}

// ---------------------------------------------------------------------------
// MFMA bf16 GEMM: 128x128 tile, BK=32, 2-buffer, 4 waves (2x2), chunk-XOR
// swizzled LDS (0 conflicts in K-loop), XCD block swizzle, (256,4).
// LDS-transpose epilogue: coalesced dwordx4 stores.
//   MODE 0: +bias ; MODE 2: +bias, exact GELU
//   OUTBF: 1 -> bf16 out, 0 -> fp32 out
// ---------------------------------------------------------------------------
template <int MODE, int OUTBF>
__global__ __launch_bounds__(256, 4) void k_mgemm(const unsigned short* __restrict__ A,
                                                  const unsigned short* __restrict__ W,
                                                  const float* __restrict__ bias,
                                                  void* __restrict__ Cout,
                                                  int M, int N, int K) {
  __shared__ short SMEM[2][2][512 * 8];
  const int tid = threadIdx.x;
  const int lane = tid & 63;
  const int wid = tid >> 6;
  const int wm = wid >> 1;
  const int wn = wid & 1;

  const int nwg = gridDim.x * gridDim.y;
  const int bid = blockIdx.y * gridDim.x + blockIdx.x;
  const int swz = (bid & 7) * (nwg >> 3) + (bid >> 3);
  const int m0 = (swz / gridDim.x) * 128;
  const int n0 = (swz % gridDim.x) * 128;

  int r0S, c0S, r1S, c1S;
  {
    int p = tid;
    int rp = p >> 3, q = (p & 7) ^ (rp & 7);
    r0S = (rp << 1) | (q >> 2);
    c0S = q & 3;
    p = tid + 256;
    rp = p >> 3;
    q = (p & 7) ^ (rp & 7);
    r1S = (rp << 1) | (q >> 2);
    c1S = q & 3;
  }
  const unsigned short* a0p = A + (size_t)(m0 + r0S) * K + c0S * 8;
  const unsigned short* a1p = A + (size_t)(m0 + r1S) * K + c1S * 8;
  const unsigned short* b0p = W + (size_t)(n0 + r0S) * K + c0S * 8;
  const unsigned short* b1p = W + (size_t)(n0 + r1S) * K + c1S * 8;
  const int d0 = (tid & ~63) * 8;
  const int d1 = ((tid + 256) & ~63) * 8;

  f32x4 acc[4][4] = {};
  const int lr = lane & 15;
  const int chr = lane >> 4;

  gload_lds16(a0p, &SMEM[0][0][d0]);
  gload_lds16(a1p, &SMEM[0][0][d1]);
  gload_lds16(b0p, &SMEM[1][0][d0]);
  gload_lds16(b1p, &SMEM[1][0][d1]);
  __syncthreads();

  const int nsteps = K >> 5;
  int buf = 0;
  for (int s = 0; s < nsteps; ++s) {
    if (s + 1 < nsteps) {
      const int ko = (s + 1) << 5;
      gload_lds16(a0p + ko, &SMEM[0][buf ^ 1][d0]);
      gload_lds16(a1p + ko, &SMEM[0][buf ^ 1][d1]);
      gload_lds16(b0p + ko, &SMEM[1][buf ^ 1][d0]);
      gload_lds16(b1p + ko, &SMEM[1][buf ^ 1][d1]);
    }
    short8 af[4], bfr[4];
#pragma unroll
    for (int mi = 0; mi < 4; ++mi)
      af[mi] = *(const short8*)&SMEM[0][buf][gperm(wm * 64 + mi * 16 + lr, chr) * 8];
#pragma unroll
    for (int ni = 0; ni < 4; ++ni)
      bfr[ni] = *(const short8*)&SMEM[1][buf][gperm(wn * 64 + ni * 16 + lr, chr) * 8];
#pragma unroll
    for (int mi = 0; mi < 4; ++mi)
#pragma unroll
      for (int ni = 0; ni < 4; ++ni)
        acc[mi][ni] = __builtin_amdgcn_mfma_f32_16x16x32_bf16(
            af[mi], bfr[ni], acc[mi][ni], 0, 0, 0);
    __syncthreads();
    buf ^= 1;
  }

  // LDS-transpose epilogue
  float* cw = (float*)&SMEM[0][0][0] + wid * (16 * 68);
  const int cj = lane & 15;
  const int rj4 = (lane >> 4) * 4;
  const int rrd = lane >> 3;
  const int crd = (lane & 7) * 8;
#pragma unroll
  for (int mi = 0; mi < 4; ++mi) {
#pragma unroll
    for (int ni = 0; ni < 4; ++ni) {
      float bn = bias[n0 + wn * 64 + ni * 16 + cj];
#pragma unroll
      for (int j = 0; j < 4; ++j) {
        float v = acc[mi][ni][j] + bn;
        if (MODE == 2) v = 0.5f * v * (1.0f + erff(v * 0.70710678118654752f));
        cw[(rj4 + j) * 68 + ni * 16 + cj] = v;
      }
    }
    __builtin_amdgcn_sched_barrier(0);
#pragma unroll
    for (int t = 0; t < 2; ++t) {
      int rl = t * 8 + rrd;
      float4v v0 = *(const float4v*)&cw[rl * 68 + crd];
      float4v v1 = *(const float4v*)&cw[rl * 68 + crd + 4];
      size_t gbase = (size_t)(m0 + wm * 64 + mi * 16 + rl) * N +
                     (n0 + wn * 64 + crd);
      if (OUTBF) {
        unsigned int w0 = ftobf(v0[0]) | ((unsigned int)ftobf(v0[1]) << 16);
        unsigned int w1 = ftobf(v0[2]) | ((unsigned int)ftobf(v0[3]) << 16);
        unsigned int w2 = ftobf(v1[0]) | ((unsigned int)ftobf(v1[1]) << 16);
        unsigned int w3 = ftobf(v1[2]) | ((unsigned int)ftobf(v1[3]) << 16);
        uint4v pk = {w0, w1, w2, w3};
        *(uint4v*)&((unsigned short*)Cout)[gbase] = pk;
      } else {
        *(float4v*)&((float*)Cout)[gbase] = v0;
        *(float4v*)&((float*)Cout)[gbase + 4] = v1;
      }
    }
    __builtin_amdgcn_sched_barrier(0);
  }
}

// ---------------------------------------------------------------------------
// Windowed causal attention, MFMA. qkv bf16 [T][1536]. PV kb-range trimmed.
// LDS 48 KB (Ps aliases Ks), 3 blocks/CU.
// ---------------------------------------------------------------------------
__global__ __launch_bounds__(256, 3) void k_attn(const unsigned short* __restrict__ qkv,
                                                 unsigned short* __restrict__ o) {
  __shared__ unsigned short KPs[192 * 64];  // K rows, then reused as P
  __shared__ unsigned short Vt[64 * 192];

  const int tid = threadIdx.x;
  const int lane = tid & 63;
  const int w = tid >> 6;
  const int idx = blockIdx.x;
  const int qb = idx & 31;
  const int hh = (idx >> 5) & 7;
  const int b = idx >> 8;
  const int q0 = qb * 64;
  const int kstart = max(0, q0 - 128);
  const int nk = q0 + 64 - kstart;  // 64 (qb==0) or 192

  for (int c = tid; c < nk * 8; c += 256) {
    int j = c >> 3, ch = c & 7;
    short8 kv = *(const short8*)&qkv[(size_t)(b * Sc + kstart + j) * QKVW + Dc + hh * DHc + ch * 8];
    *(short8*)&KPs[swzK(j, ch * 8)] = kv;
  }
  for (int c = tid; c < (nk >> 1) * 8; c += 256) {
    int jp = c >> 3, ch = c & 7;
    int j = jp * 2;
    const unsigned short* base =
        &qkv[(size_t)(b * Sc + kstart + j) * QKVW + 2 * Dc + hh * DHc + ch * 8];
    short8 v0 = *(const short8*)base;
    short8 v1 = *(const short8*)(base + QKVW);
#pragma unroll
    for (int i = 0; i < 8; ++i) {
      unsigned int pk = (unsigned short)v0[i] | ((unsigned int)(unsigned short)v1[i] << 16);
      *(unsigned int*)&Vt[swzW(ch * 8 + i, j)] = pk;
    }
  }
  if (nk < 192) {  // qb==0: zero Vt cols [64,192) so P*garbage can't NaN
    for (int c = tid; c < 64 * 64; c += 256) {
      int d = c >> 6, jo = c & 63;
      *(unsigned int*)&Vt[swzW(d, 64 + jo * 2)] = 0;
    }
  }

  const int qg = q0 + w * 16 + (lane & 15);
  const int kg8 = (lane >> 4) * 8;
  const unsigned short* qp = &qkv[(size_t)(b * Sc + qg) * QKVW + hh * DHc + kg8];
  short8 bq0 = *(const short8*)qp;
  short8 bq1 = *(const short8*)(qp + 32);
  __syncthreads();

  const int jb = max(0, q0 + w * 16 - 128) - kstart;

  f32x4 sacc[9];
#pragma unroll
  for (int t = 0; t < 9; ++t) {
    int key = jb + t * 16 + (lane & 15);
    short8 a0 = *(const short8*)&KPs[swzK(key, kg8)];
    short8 a1 = *(const short8*)&KPs[swzK(key, 32 + kg8)];
    f32x4 z = {0.f, 0.f, 0.f, 0.f};
    z = __builtin_amdgcn_mfma_f32_16x16x32_bf16(a0, bq0, z, 0, 0, 0);
    sacc[t] = __builtin_amdgcn_mfma_f32_16x16x32_bf16(a1, bq1, z, 0, 0, 0);
  }

  const int rj = (lane >> 4) * 4;
  float mx = -1e30f;
#pragma unroll
  for (int t = 0; t < 9; ++t) {
#pragma unroll
    for (int j = 0; j < 4; ++j) {
      int kglob = kstart + jb + t * 16 + rj + j;
      bool valid = (kglob <= qg) && (kglob + 128 >= qg);
      float s = valid ? sacc[t][j] * 0.125f : -1e30f;
      sacc[t][j] = s;
      mx = fmaxf(mx, s);
    }
  }
  mx = fmaxf(mx, __shfl_xor(mx, 16));
  mx = fmaxf(mx, __shfl_xor(mx, 32));
  float sum = 0.f;
#pragma unroll
  for (int t = 0; t < 9; ++t)
#pragma unroll
    for (int j = 0; j < 4; ++j) {
      float e = __expf(sacc[t][j] - mx);
      sacc[t][j] = e;
      sum += e;
    }
  sum += __shfl_xor(sum, 16);
  sum += __shfl_xor(sum, 32);
  const float inv = 1.0f / sum;

  // all K reads complete; hand KPs over to P storage
  __syncthreads();

  const int prow = w * 16 + (lane & 15);
#pragma unroll
  for (int t = 0; t < 9; ++t) {
    int c0 = jb + t * 16 + rj;
    unsigned int p0 = ftobf(sacc[t][0] * inv) |
                      ((unsigned int)ftobf(sacc[t][1] * inv) << 16);
    unsigned int p1 = ftobf(sacc[t][2] * inv) |
                      ((unsigned int)ftobf(sacc[t][3] * inv) << 16);
    *(unsigned int*)&KPs[swzW(prow, c0)] = p0;
    *(unsigned int*)&KPs[swzW(prow, c0 + 2)] = p1;
  }
  {
    int g2 = (lane >> 4) * 2;
    for (int col = g2; col < jb; col += 8)
      *(unsigned int*)&KPs[swzW(prow, col)] = 0;
    for (int col = jb + 144 + g2; col < 192; col += 8)
      *(unsigned int*)&KPs[swzW(prow, col)] = 0;
  }
  // PV over the wave's valid kb range only
  const int kb0 = jb >> 5;
  const int kbend = min(6, (jb + 144 + 31) >> 5);
  f32x4 oacc[4] = {};
  for (int kb = kb0; kb < kbend; ++kb) {
    short8 pa = *(const short8*)&KPs[swzW(prow, kb * 32 + kg8)];
#pragma unroll
    for (int dt = 0; dt < 4; ++dt) {
      short8 vb = *(const short8*)&Vt[swzW(dt * 16 + (lane & 15), kb * 32 + kg8)];
      oacc[dt] = __builtin_amdgcn_mfma_f32_16x16x32_bf16(pa, vb, oacc[dt], 0, 0, 0);
    }
  }
  const int cj = lane & 15;
#pragma unroll
  for (int j = 0; j < 4; ++j)
#pragma unroll
    for (int dt = 0; dt < 4; ++dt)
      o[(size_t)(b * Sc + q0 + w * 16 + rj + j) * Dc + hh * DHc + dt * 16 + cj] =
          ftobf(oacc[dt][j]);
}

// ---------------------------------------------------------------------------
// Residual + LayerNorm: h = LN(h + raw) over D=512; writes h fp32 + hb bf16.
// ---------------------------------------------------------------------------
__global__ __launch_bounds__(256) void k_lnr(float* __restrict__ h,
                                             const float* __restrict__ raw,
                                             const float* __restrict__ g,
                                             const float* __restrict__ bta,
                                             unsigned short* __restrict__ outb) {
  const int wid = threadIdx.x >> 6;
  const int lane = threadIdx.x & 63;
  const int t = blockIdx.x * 4 + wid;
  const float4v* hrow = (const float4v*)(h + (size_t)t * Dc);
  const float4v* rrow = (const float4v*)(raw + (size_t)t * Dc);
  float4v v[2];
  float sum = 0.0f, sq = 0.0f;
#pragma unroll
  for (int i = 0; i < 2; ++i) {
    float4v hv = hrow[lane + i * 64];
    float4v rv = rrow[lane + i * 64];
#pragma unroll
    for (int c = 0; c < 4; ++c) {
      float xv = rv[c] + hv[c];
      v[i][c] = xv;
      sum += xv;
      sq += xv * xv;
    }
  }
#pragma unroll
  for (int off = 32; off; off >>= 1) {
    sum += __shfl_xor(sum, off);
    sq += __shfl_xor(sq, off);
  }
  float m = sum * (1.0f / 512.0f);
  float var = sq * (1.0f / 512.0f) - m * m;
  float rstd = rsqrtf(var + 1e-5f);
  float4v* orow = (float4v*)(h + (size_t)t * Dc);
  unsigned int* brow = (unsigned int*)(outb + (size_t)t * Dc);
#pragma unroll
  for (int i = 0; i < 2; ++i) {
    int d4 = (lane + i * 64) * 4;
    float4v ov;
#pragma unroll
    for (int c = 0; c < 4; ++c)
      ov[c] = (v[i][c] - m) * rstd * g[d4 + c] + bta[d4 + c];
    orow[lane + i * 64] = ov;
    unsigned int p0 = ftobf(ov[0]) | ((unsigned int)ftobf(ov[1]) << 16);
    unsigned int p1 = ftobf(ov[2]) | ((unsigned int)ftobf(ov[3]) << 16);
    brow[(lane + i * 64) * 2] = p0;
    brow[(lane + i * 64) * 2 + 1] = p1;
  }
}

// ---------------------------------------------------------------------------
// Head (fp32): mu | clipped log_sigma
// ---------------------------------------------------------------------------
__global__ __launch_bounds__(256) void k_head(const float* __restrict__ h,
                                              const float* __restrict__ Wh,
                                              const float* __restrict__ bh,
                                              float* __restrict__ outp) {
  const int wid = threadIdx.x >> 6;
  const int lane = threadIdx.x & 63;
  const int t = blockIdx.x * 4 + wid;
  const float* row = h + (size_t)t * Dc;
  float a0 = 0, a1 = 0, a2 = 0, a3 = 0;
#pragma unroll
  for (int i = 0; i < 8; ++i) {
    int d = lane + i * 64;
    float xv = row[d];
    a0 += xv * Wh[0 * Dc + d];
    a1 += xv * Wh[1 * Dc + d];
    a2 += xv * Wh[2 * Dc + d];
    a3 += xv * Wh[3 * Dc + d];
  }
#pragma unroll
  for (int off = 32; off; off >>= 1) {
    a0 += __shfl_xor(a0, off);
    a1 += __shfl_xor(a1, off);
    a2 += __shfl_xor(a2, off);
    a3 += __shfl_xor(a3, off);
  }
  if (lane == 0) {
    outp[(size_t)t * 2 + 0] = a0 + bh[0];
    outp[(size_t)t * 2 + 1] = a1 + bh[1];
    outp[(size_t)Tc * 2 + (size_t)t * 2 + 0] = fminf(fmaxf(a2 + bh[2], -6.0f), 1.5f);
    outp[(size_t)Tc * 2 + (size_t)t * 2 + 1] = fminf(fmaxf(a3 + bh[3], -6.0f), 1.5f);
  }
}

// ---------------------------------------------------------------------------
extern "C" void kernel_launch(void* const* d_in, const int* in_sizes, int n_in,
                              void* d_out, int out_size, void* d_ws, size_t ws_size,
                              hipStream_t stream) {
  const float* x    = (const float*)d_in[0];
  const float* W_in = (const float*)d_in[1];
  const float* b_in = (const float*)d_in[2];
  const float* pos  = (const float*)d_in[3];
  const float* Wqkv = (const float*)d_in[4];
  const float* bqkv = (const float*)d_in[5];
  const float* Wo   = (const float*)d_in[6];
  const float* bo   = (const float*)d_in[7];
  const float* W1   = (const float*)d_in[8];
  const float* b1   = (const float*)d_in[9];
  const float* W2   = (const float*)d_in[10];
  const float* b2   = (const float*)d_in[11];
  const float* ln1g = (const float*)d_in[12];
  const float* ln1b = (const float*)d_in[13];
  const float* ln2g = (const float*)d_in[14];
  const float* ln2b = (const float*)d_in[15];
  const float* Wh   = (const float*)d_in[16];
  const float* bh   = (const float*)d_in[17];
  float* out = (float*)d_out;

  char* p = (char*)d_ws;
  float* h   = (float*)p;          p += (size_t)Tc * Dc * 4;   // residual stream fp32
  float* t2  = (float*)p;          p += (size_t)Tc * Dc * 4;   // raw GEMM out fp32
  unsigned short* hb  = (unsigned short*)p; p += (size_t)Tc * Dc * 2;
  unsigned short* ob  = (unsigned short*)p; p += (size_t)Tc * Dc * 2;
  unsigned short* big = (unsigned short*)p; p += (size_t)Tc * DFFc * 2;
  unsigned short* wqb = (unsigned short*)p; p += (size_t)Lc * QKVW * Dc * 2;
  unsigned short* wob = (unsigned short*)p; p += (size_t)Lc * Dc * Dc * 2;
  unsigned short* w1b = (unsigned short*)p; p += (size_t)Lc * DFFc * Dc * 2;
  unsigned short* w2b = (unsigned short*)p; p += (size_t)Lc * Dc * DFFc * 2;

  // merged weight conversion: 1 launch (x4 vectorized)
  const int nq = Lc * QKVW * Dc;          // 3,145,728
  const int no = Lc * Dc * Dc;            // 1,048,576
  const int n1 = Lc * DFFc * Dc;          // 4,194,304
  const int n2 = Lc * Dc * DFFc;          // 4,194,304
  const int ntot = nq + no + n1 + n2;     // 12,582,912
  k_f2bf4<<<ntot / 1024, 256, 0, stream>>>(Wqkv, Wo, W1, W2, wqb, wob, w1b, w2b,
                                           nq, nq + no, nq + no + n1, ntot);

  k_embed<<<(Tc * Dc) / 1024, 256, 0, stream>>>(x, W_in, b_in, pos, h, hb);

  for (int l = 0; l < Lc; ++l) {
    const unsigned short* wq_l = wqb + (size_t)l * QKVW * Dc;
    const unsigned short* wo_l = wob + (size_t)l * Dc * Dc;
    const unsigned short* w1_l = w1b + (size_t)l * DFFc * Dc;
    const unsigned short* w2_l = w2b + (size_t)l * Dc * DFFc;

    // qkv = hb @ Wqkv^T + bqkv  (bf16 out)
    k_mgemm<0, 1><<<dim3(QKVW / 128, Tc / 128), 256, 0, stream>>>(
        hb, wq_l, bqkv + (size_t)l * QKVW, big, Tc, QKVW, Dc);

    k_attn<<<Bc * Hc * (Sc / 64), 256, 0, stream>>>(big, ob);

    // t2 = ob @ Wo^T + bo  (fp32 raw; residual added in LN)
    k_mgemm<0, 0><<<dim3(Dc / 128, Tc / 128), 256, 0, stream>>>(
        ob, wo_l, bo + (size_t)l * Dc, t2, Tc, Dc, Dc);

    // h = LN1(h + t2); hb = bf16(h)
    k_lnr<<<Tc / 4, 256, 0, stream>>>(h, t2, ln1g + (size_t)l * Dc,
                                      ln1b + (size_t)l * Dc, hb);

    // big = gelu(hb @ W1^T + b1)  (bf16 out)
    k_mgemm<2, 1><<<dim3(DFFc / 128, Tc / 128), 256, 0, stream>>>(
        hb, w1_l, b1 + (size_t)l * DFFc, big, Tc, DFFc, Dc);

    // t2 = big @ W2^T + b2  (fp32 raw)
    k_mgemm<0, 0><<<dim3(Dc / 128, Tc / 128), 256, 0, stream>>>(
        big, w2_l, b2 + (size_t)l * Dc, t2, Tc, Dc, DFFc);

    // h = LN2(h + t2); hb = bf16(h)
    k_lnr<<<Tc / 4, 256, 0, stream>>>(h, t2, ln2g + (size_t)l * Dc,
                                      ln2b + (size_t)l * Dc, hb);
  }

  k_head<<<Tc / 4, 256, 0, stream>>>(h, Wh, bh, out);
}

// Round 14
// 574.165 us; speedup vs baseline: 1.0680x; 1.0317x over previous
//
#include <hip/hip_runtime.h>
#include <hip/hip_bf16.h>
#include <math.h>

// Problem constants
constexpr int Bc = 4;
constexpr int Sc = 2048;
constexpr int Dc = 512;
constexpr int Hc = 8;
constexpr int DHc = 64;
constexpr int Lc = 4;
constexpr int DFFc = 2048;
constexpr int Tc = Bc * Sc;   // 8192 tokens
constexpr int QKVW = 3 * Dc;  // 1536

typedef __attribute__((ext_vector_type(8))) short short8;
typedef __attribute__((ext_vector_type(4))) float f32x4;
typedef __attribute__((ext_vector_type(4))) float float4v;
typedef __attribute__((ext_vector_type(4))) unsigned int uint4v;
typedef __attribute__((ext_vector_type(2))) unsigned int uint2v;

static __device__ __forceinline__ float u16tof(unsigned int u) {
  return __uint_as_float(u << 16);
}
static __device__ __forceinline__ unsigned short ftobf(float f) {
  __hip_bfloat16 h = __float2bfloat16(f);
  return *reinterpret_cast<unsigned short*>(&h);
}
static __device__ __forceinline__ void gload_lds16(const void* g, void* l) {
  __builtin_amdgcn_global_load_lds(
      (const __attribute__((address_space(1))) void*)g,
      (__attribute__((address_space(3))) void*)l, 16, 0, 0);
}

// LDS chunk-swizzle helpers for attention (16B-chunk XOR, conflict-free b128)
static __device__ __forceinline__ int swzK(int row, int col) {  // width 64
  return row * 64 + ((((col >> 3) ^ (row & 7)) << 3) | (col & 7));
}
static __device__ __forceinline__ int swzW(int row, int col) {  // width 192
  return row * 192 + ((((col >> 3) ^ (row & 7)) << 3) | (col & 7));
}
// GEMM-family granule permutation
static __device__ __forceinline__ int gperm(int row, int ch) {
  return (row >> 1) * 8 + (((((row & 1) << 2) | ch)) ^ ((row >> 1) & 7));
}

// ---------------------------------------------------------------------------
// Merged fp32 -> bf16 weight conversion (all 4 tensors, one launch, x4 vec)
// ---------------------------------------------------------------------------
__global__ __launch_bounds__(256) void k_f2bf4(const float* __restrict__ p0,
                                               const float* __restrict__ p1,
                                               const float* __restrict__ p2,
                                               const float* __restrict__ p3,
                                               unsigned short* __restrict__ o0,
                                               unsigned short* __restrict__ o1,
                                               unsigned short* __restrict__ o2,
                                               unsigned short* __restrict__ o3,
                                               int n0, int n01, int n012, int n0123) {
  int i4 = (blockIdx.x * 256 + threadIdx.x) * 4;
  if (i4 >= n0123) return;
  const float* src;
  unsigned short* dst;
  int off;
  if (i4 < n0) { src = p0; dst = o0; off = i4; }
  else if (i4 < n01) { src = p1; dst = o1; off = i4 - n0; }
  else if (i4 < n012) { src = p2; dst = o2; off = i4 - n01; }
  else { src = p3; dst = o3; off = i4 - n012; }
  float4v v = *(const float4v*)&src[off];
  uint2v pk = {ftobf(v[0]) | ((unsigned int)ftobf(v[1]) << 16),
               ftobf(v[2]) | ((unsigned int)ftobf(v[3]) << 16)};
  *(uint2v*)&dst[off] = pk;
}

// ---------------------------------------------------------------------------
// Embed (vectorized x4): h = x @ W_in^T + b_in + pos ; also bf16 copy
// ---------------------------------------------------------------------------
__global__ __launch_bounds__(256) void k_embed(const float* __restrict__ x,
                                               const float* __restrict__ W_in,
                                               const float* __restrict__ b_in,
                                               const float* __restrict__ pos,
                                               float* __restrict__ h,
                                               unsigned short* __restrict__ hb) {
  int i4 = (blockIdx.x * 256 + threadIdx.x) * 4;
  int t = i4 >> 9;
  int d = i4 & 511;
  int s = t & (Sc - 1);
  float x0 = x[t * 2 + 0], x1 = x[t * 2 + 1];
  float4v w01 = *(const float4v*)&W_in[d * 2];
  float4v w23 = *(const float4v*)&W_in[d * 2 + 4];
  float4v pz = *(const float4v*)&pos[(size_t)s * Dc + d];
  float4v b4 = *(const float4v*)&b_in[d];
  float4v v;
  v[0] = x0 * w01[0] + x1 * w01[1] + b4[0] + pz[0];
  v[1] = x0 * w01[2] + x1 * w01[3] + b4[1] + pz[1];
  v[2] = x0 * w23[0] + x1 * w23[1] + b4[2] + pz[2];
  v[3] = x0 * w23[2] + x1 * w23[3] + b4[3] + pz[3];
  *(float4v*)&h[i4] = v;
  uint2v pk = {ftobf(v[0]) | ((unsigned int)ftobf(v[1]) << 16),
               ftobf(v[2]) | ((unsigned int)ftobf(v[3]) << 16)};
  *(uint2v*)&hb[i4] = pk;
}

// ---------------------------------------------------------------------------
// MFMA bf16 GEMM: 128x128 tile, BK=32, 4 waves (2x2), chunk-XOR swizzled LDS,
// XCD block swizzle. NEW: TRIPLE-buffered counted-vmcnt pipeline — no
// __syncthreads vmcnt(0) drain in the K-loop. Tile s+2 staged at step s;
// per-step wait = vmcnt(4) (tile s+1 stays in flight), raw s_barrier.
// 48 KB LDS -> 3 blocks/CU at (256,3). Overwrite safety: buf (s+2)%3 was
// last ds_read at step s-1; every wave lgkmcnt(0)s those reads BEFORE its
// top-of-step-s barrier arrival, after which the stage is issued.
// LDS-transpose epilogue: coalesced dwordx4 stores (bit-identical to r13).
//   MODE 0: +bias ; MODE 2: +bias, exact GELU
//   OUTBF: 1 -> bf16 out, 0 -> fp32 out
// ---------------------------------------------------------------------------
template <int MODE, int OUTBF>
__global__ __launch_bounds__(256, 3) void k_mgemm(const unsigned short* __restrict__ A,
                                                  const unsigned short* __restrict__ W,
                                                  const float* __restrict__ bias,
                                                  void* __restrict__ Cout,
                                                  int M, int N, int K) {
  __shared__ short SMEM[3][2][512 * 8];  // [buf][A/B][8KB] = 48 KB
  const int tid = threadIdx.x;
  const int lane = tid & 63;
  const int wid = tid >> 6;
  const int wm = wid >> 1;
  const int wn = wid & 1;

  const int nwg = gridDim.x * gridDim.y;
  const int bid = blockIdx.y * gridDim.x + blockIdx.x;
  const int swz = (bid & 7) * (nwg >> 3) + (bid >> 3);
  const int m0 = (swz / gridDim.x) * 128;
  const int n0 = (swz % gridDim.x) * 128;

  int r0S, c0S, r1S, c1S;
  {
    int p = tid;
    int rp = p >> 3, q = (p & 7) ^ (rp & 7);
    r0S = (rp << 1) | (q >> 2);
    c0S = q & 3;
    p = tid + 256;
    rp = p >> 3;
    q = (p & 7) ^ (rp & 7);
    r1S = (rp << 1) | (q >> 2);
    c1S = q & 3;
  }
  const unsigned short* a0p = A + (size_t)(m0 + r0S) * K + c0S * 8;
  const unsigned short* a1p = A + (size_t)(m0 + r1S) * K + c1S * 8;
  const unsigned short* b0p = W + (size_t)(n0 + r0S) * K + c0S * 8;
  const unsigned short* b1p = W + (size_t)(n0 + r1S) * K + c1S * 8;
  const int d0 = (tid & ~63) * 8;
  const int d1 = ((tid + 256) & ~63) * 8;

  f32x4 acc[4][4] = {};
  const int lr = lane & 15;
  const int chr = lane >> 4;

  // prologue: stage tiles 0 and 1 (8 loads in flight)
#pragma unroll
  for (int t = 0; t < 2; ++t) {
    const int ko = t << 5;
    gload_lds16(a0p + ko, &SMEM[t][0][d0]);
    gload_lds16(a1p + ko, &SMEM[t][0][d1]);
    gload_lds16(b0p + ko, &SMEM[t][1][d0]);
    gload_lds16(b1p + ko, &SMEM[t][1][d1]);
  }

  const int nsteps = K >> 5;
  for (int s = 0; s < nsteps; ++s) {
    // wait for tile s only; tile s+1 stays in flight (no vmcnt(0) drain)
    if (s + 1 < nsteps)
      asm volatile("s_waitcnt vmcnt(4)" ::: "memory");
    else
      asm volatile("s_waitcnt vmcnt(0)" ::: "memory");
    __builtin_amdgcn_s_barrier();
    __builtin_amdgcn_sched_barrier(0);

    // stage tile s+2 into buf (s+2)%3 (that buf's reads finished at step s-1)
    if (s + 2 < nsteps) {
      const int ko = (s + 2) << 5;
      const int nb = (s + 2) % 3;
      gload_lds16(a0p + ko, &SMEM[nb][0][d0]);
      gload_lds16(a1p + ko, &SMEM[nb][0][d1]);
      gload_lds16(b0p + ko, &SMEM[nb][1][d0]);
      gload_lds16(b1p + ko, &SMEM[nb][1][d1]);
    }

    const int buf = s % 3;
    short8 af[4], bfr[4];
#pragma unroll
    for (int mi = 0; mi < 4; ++mi)
      af[mi] = *(const short8*)&SMEM[buf][0][gperm(wm * 64 + mi * 16 + lr, chr) * 8];
#pragma unroll
    for (int ni = 0; ni < 4; ++ni)
      bfr[ni] = *(const short8*)&SMEM[buf][1][gperm(wn * 64 + ni * 16 + lr, chr) * 8];
    asm volatile("s_waitcnt lgkmcnt(0)" ::: "memory");
    __builtin_amdgcn_sched_barrier(0);
#pragma unroll
    for (int mi = 0; mi < 4; ++mi)
#pragma unroll
      for (int ni = 0; ni < 4; ++ni)
        acc[mi][ni] = __builtin_amdgcn_mfma_f32_16x16x32_bf16(
            af[mi], bfr[ni], acc[mi][ni], 0, 0, 0);
  }
  __syncthreads();  // all waves done with LDS before epilogue scratch reuse

  // LDS-transpose epilogue (identical to r13)
  float* cw = (float*)&SMEM[0][0][0] + wid * (16 * 68);
  const int cj = lane & 15;
  const int rj4 = (lane >> 4) * 4;
  const int rrd = lane >> 3;
  const int crd = (lane & 7) * 8;
#pragma unroll
  for (int mi = 0; mi < 4; ++mi) {
#pragma unroll
    for (int ni = 0; ni < 4; ++ni) {
      float bn = bias[n0 + wn * 64 + ni * 16 + cj];
#pragma unroll
      for (int j = 0; j < 4; ++j) {
        float v = acc[mi][ni][j] + bn;
        if (MODE == 2) v = 0.5f * v * (1.0f + erff(v * 0.70710678118654752f));
        cw[(rj4 + j) * 68 + ni * 16 + cj] = v;
      }
    }
    __builtin_amdgcn_sched_barrier(0);
#pragma unroll
    for (int t = 0; t < 2; ++t) {
      int rl = t * 8 + rrd;
      float4v v0 = *(const float4v*)&cw[rl * 68 + crd];
      float4v v1 = *(const float4v*)&cw[rl * 68 + crd + 4];
      size_t gbase = (size_t)(m0 + wm * 64 + mi * 16 + rl) * N +
                     (n0 + wn * 64 + crd);
      if (OUTBF) {
        unsigned int w0 = ftobf(v0[0]) | ((unsigned int)ftobf(v0[1]) << 16);
        unsigned int w1 = ftobf(v0[2]) | ((unsigned int)ftobf(v0[3]) << 16);
        unsigned int w2 = ftobf(v1[0]) | ((unsigned int)ftobf(v1[1]) << 16);
        unsigned int w3 = ftobf(v1[2]) | ((unsigned int)ftobf(v1[3]) << 16);
        uint4v pk = {w0, w1, w2, w3};
        *(uint4v*)&((unsigned short*)Cout)[gbase] = pk;
      } else {
        *(float4v*)&((float*)Cout)[gbase] = v0;
        *(float4v*)&((float*)Cout)[gbase + 4] = v1;
      }
    }
    __builtin_amdgcn_sched_barrier(0);
  }
}

// ---------------------------------------------------------------------------
// Windowed causal attention, MFMA. qkv bf16 [T][1536]. PV kb-range trimmed.
// LDS 48 KB (Ps aliases Ks), 3 blocks/CU.
// ---------------------------------------------------------------------------
__global__ __launch_bounds__(256, 3) void k_attn(const unsigned short* __restrict__ qkv,
                                                 unsigned short* __restrict__ o) {
  __shared__ unsigned short KPs[192 * 64];  // K rows, then reused as P
  __shared__ unsigned short Vt[64 * 192];

  const int tid = threadIdx.x;
  const int lane = tid & 63;
  const int w = tid >> 6;
  const int idx = blockIdx.x;
  const int qb = idx & 31;
  const int hh = (idx >> 5) & 7;
  const int b = idx >> 8;
  const int q0 = qb * 64;
  const int kstart = max(0, q0 - 128);
  const int nk = q0 + 64 - kstart;  // 64 (qb==0) or 192

  for (int c = tid; c < nk * 8; c += 256) {
    int j = c >> 3, ch = c & 7;
    short8 kv = *(const short8*)&qkv[(size_t)(b * Sc + kstart + j) * QKVW + Dc + hh * DHc + ch * 8];
    *(short8*)&KPs[swzK(j, ch * 8)] = kv;
  }
  for (int c = tid; c < (nk >> 1) * 8; c += 256) {
    int jp = c >> 3, ch = c & 7;
    int j = jp * 2;
    const unsigned short* base =
        &qkv[(size_t)(b * Sc + kstart + j) * QKVW + 2 * Dc + hh * DHc + ch * 8];
    short8 v0 = *(const short8*)base;
    short8 v1 = *(const short8*)(base + QKVW);
#pragma unroll
    for (int i = 0; i < 8; ++i) {
      unsigned int pk = (unsigned short)v0[i] | ((unsigned int)(unsigned short)v1[i] << 16);
      *(unsigned int*)&Vt[swzW(ch * 8 + i, j)] = pk;
    }
  }
  if (nk < 192) {  // qb==0: zero Vt cols [64,192) so P*garbage can't NaN
    for (int c = tid; c < 64 * 64; c += 256) {
      int d = c >> 6, jo = c & 63;
      *(unsigned int*)&Vt[swzW(d, 64 + jo * 2)] = 0;
    }
  }

  const int qg = q0 + w * 16 + (lane & 15);
  const int kg8 = (lane >> 4) * 8;
  const unsigned short* qp = &qkv[(size_t)(b * Sc + qg) * QKVW + hh * DHc + kg8];
  short8 bq0 = *(const short8*)qp;
  short8 bq1 = *(const short8*)(qp + 32);
  __syncthreads();

  const int jb = max(0, q0 + w * 16 - 128) - kstart;

  f32x4 sacc[9];
#pragma unroll
  for (int t = 0; t < 9; ++t) {
    int key = jb + t * 16 + (lane & 15);
    short8 a0 = *(const short8*)&KPs[swzK(key, kg8)];
    short8 a1 = *(const short8*)&KPs[swzK(key, 32 + kg8)];
    f32x4 z = {0.f, 0.f, 0.f, 0.f};
    z = __builtin_amdgcn_mfma_f32_16x16x32_bf16(a0, bq0, z, 0, 0, 0);
    sacc[t] = __builtin_amdgcn_mfma_f32_16x16x32_bf16(a1, bq1, z, 0, 0, 0);
  }

  const int rj = (lane >> 4) * 4;
  float mx = -1e30f;
#pragma unroll
  for (int t = 0; t < 9; ++t) {
#pragma unroll
    for (int j = 0; j < 4; ++j) {
      int kglob = kstart + jb + t * 16 + rj + j;
      bool valid = (kglob <= qg) && (kglob + 128 >= qg);
      float s = valid ? sacc[t][j] * 0.125f : -1e30f;
      sacc[t][j] = s;
      mx = fmaxf(mx, s);
    }
  }
  mx = fmaxf(mx, __shfl_xor(mx, 16));
  mx = fmaxf(mx, __shfl_xor(mx, 32));
  float sum = 0.f;
#pragma unroll
  for (int t = 0; t < 9; ++t)
#pragma unroll
    for (int j = 0; j < 4; ++j) {
      float e = __expf(sacc[t][j] - mx);
      sacc[t][j] = e;
      sum += e;
    }
  sum += __shfl_xor(sum, 16);
  sum += __shfl_xor(sum, 32);
  const float inv = 1.0f / sum;

  // all K reads complete; hand KPs over to P storage
  __syncthreads();

  const int prow = w * 16 + (lane & 15);
#pragma unroll
  for (int t = 0; t < 9; ++t) {
    int c0 = jb + t * 16 + rj;
    unsigned int p0 = ftobf(sacc[t][0] * inv) |
                      ((unsigned int)ftobf(sacc[t][1] * inv) << 16);
    unsigned int p1 = ftobf(sacc[t][2] * inv) |
                      ((unsigned int)ftobf(sacc[t][3] * inv) << 16);
    *(unsigned int*)&KPs[swzW(prow, c0)] = p0;
    *(unsigned int*)&KPs[swzW(prow, c0 + 2)] = p1;
  }
  {
    int g2 = (lane >> 4) * 2;
    for (int col = g2; col < jb; col += 8)
      *(unsigned int*)&KPs[swzW(prow, col)] = 0;
    for (int col = jb + 144 + g2; col < 192; col += 8)
      *(unsigned int*)&KPs[swzW(prow, col)] = 0;
  }
  // PV over the wave's valid kb range only
  const int kb0 = jb >> 5;
  const int kbend = min(6, (jb + 144 + 31) >> 5);
  f32x4 oacc[4] = {};
  for (int kb = kb0; kb < kbend; ++kb) {
    short8 pa = *(const short8*)&KPs[swzW(prow, kb * 32 + kg8)];
#pragma unroll
    for (int dt = 0; dt < 4; ++dt) {
      short8 vb = *(const short8*)&Vt[swzW(dt * 16 + (lane & 15), kb * 32 + kg8)];
      oacc[dt] = __builtin_amdgcn_mfma_f32_16x16x32_bf16(pa, vb, oacc[dt], 0, 0, 0);
    }
  }
  const int cj = lane & 15;
#pragma unroll
  for (int j = 0; j < 4; ++j)
#pragma unroll
    for (int dt = 0; dt < 4; ++dt)
      o[(size_t)(b * Sc + q0 + w * 16 + rj + j) * Dc + hh * DHc + dt * 16 + cj] =
          ftobf(oacc[dt][j]);
}

// ---------------------------------------------------------------------------
// Residual + LayerNorm: h = LN(h + raw) over D=512; writes h fp32 + hb bf16.
// ---------------------------------------------------------------------------
__global__ __launch_bounds__(256) void k_lnr(float* __restrict__ h,
                                             const float* __restrict__ raw,
                                             const float* __restrict__ g,
                                             const float* __restrict__ bta,
                                             unsigned short* __restrict__ outb) {
  const int wid = threadIdx.x >> 6;
  const int lane = threadIdx.x & 63;
  const int t = blockIdx.x * 4 + wid;
  const float4v* hrow = (const float4v*)(h + (size_t)t * Dc);
  const float4v* rrow = (const float4v*)(raw + (size_t)t * Dc);
  float4v v[2];
  float sum = 0.0f, sq = 0.0f;
#pragma unroll
  for (int i = 0; i < 2; ++i) {
    float4v hv = hrow[lane + i * 64];
    float4v rv = rrow[lane + i * 64];
#pragma unroll
    for (int c = 0; c < 4; ++c) {
      float xv = rv[c] + hv[c];
      v[i][c] = xv;
      sum += xv;
      sq += xv * xv;
    }
  }
#pragma unroll
  for (int off = 32; off; off >>= 1) {
    sum += __shfl_xor(sum, off);
    sq += __shfl_xor(sq, off);
  }
  float m = sum * (1.0f / 512.0f);
  float var = sq * (1.0f / 512.0f) - m * m;
  float rstd = rsqrtf(var + 1e-5f);
  float4v* orow = (float4v*)(h + (size_t)t * Dc);
  unsigned int* brow = (unsigned int*)(outb + (size_t)t * Dc);
#pragma unroll
  for (int i = 0; i < 2; ++i) {
    int d4 = (lane + i * 64) * 4;
    float4v ov;
#pragma unroll
    for (int c = 0; c < 4; ++c)
      ov[c] = (v[i][c] - m) * rstd * g[d4 + c] + bta[d4 + c];
    orow[lane + i * 64] = ov;
    unsigned int p0 = ftobf(ov[0]) | ((unsigned int)ftobf(ov[1]) << 16);
    unsigned int p1 = ftobf(ov[2]) | ((unsigned int)ftobf(ov[3]) << 16);
    brow[(lane + i * 64) * 2] = p0;
    brow[(lane + i * 64) * 2 + 1] = p1;
  }
}

// ---------------------------------------------------------------------------
// Head (fp32): mu | clipped log_sigma
// ---------------------------------------------------------------------------
__global__ __launch_bounds__(256) void k_head(const float* __restrict__ h,
                                              const float* __restrict__ Wh,
                                              const float* __restrict__ bh,
                                              float* __restrict__ outp) {
  const int wid = threadIdx.x >> 6;
  const int lane = threadIdx.x & 63;
  const int t = blockIdx.x * 4 + wid;
  const float* row = h + (size_t)t * Dc;
  float a0 = 0, a1 = 0, a2 = 0, a3 = 0;
#pragma unroll
  for (int i = 0; i < 8; ++i) {
    int d = lane + i * 64;
    float xv = row[d];
    a0 += xv * Wh[0 * Dc + d];
    a1 += xv * Wh[1 * Dc + d];
    a2 += xv * Wh[2 * Dc + d];
    a3 += xv * Wh[3 * Dc + d];
  }
#pragma unroll
  for (int off = 32; off; off >>= 1) {
    a0 += __shfl_xor(a0, off);
    a1 += __shfl_xor(a1, off);
    a2 += __shfl_xor(a2, off);
    a3 += __shfl_xor(a3, off);
  }
  if (lane == 0) {
    outp[(size_t)t * 2 + 0] = a0 + bh[0];
    outp[(size_t)t * 2 + 1] = a1 + bh[1];
    outp[(size_t)Tc * 2 + (size_t)t * 2 + 0] = fminf(fmaxf(a2 + bh[2], -6.0f), 1.5f);
    outp[(size_t)Tc * 2 + (size_t)t * 2 + 1] = fminf(fmaxf(a3 + bh[3], -6.0f), 1.5f);
  }
}

// ---------------------------------------------------------------------------
extern "C" void kernel_launch(void* const* d_in, const int* in_sizes, int n_in,
                              void* d_out, int out_size, void* d_ws, size_t ws_size,
                              hipStream_t stream) {
  const float* x    = (const float*)d_in[0];
  const float* W_in = (const float*)d_in[1];
  const float* b_in = (const float*)d_in[2];
  const float* pos  = (const float*)d_in[3];
  const float* Wqkv = (const float*)d_in[4];
  const float* bqkv = (const float*)d_in[5];
  const float* Wo   = (const float*)d_in[6];
  const float* bo   = (const float*)d_in[7];
  const float* W1   = (const float*)d_in[8];
  const float* b1   = (const float*)d_in[9];
  const float* W2   = (const float*)d_in[10];
  const float* b2   = (const float*)d_in[11];
  const float* ln1g = (const float*)d_in[12];
  const float* ln1b = (const float*)d_in[13];
  const float* ln2g = (const float*)d_in[14];
  const float* ln2b = (const float*)d_in[15];
  const float* Wh   = (const float*)d_in[16];
  const float* bh   = (const float*)d_in[17];
  float* out = (float*)d_out;

  char* p = (char*)d_ws;
  float* h   = (float*)p;          p += (size_t)Tc * Dc * 4;   // residual stream fp32
  float* t2  = (float*)p;          p += (size_t)Tc * Dc * 4;   // raw GEMM out fp32
  unsigned short* hb  = (unsigned short*)p; p += (size_t)Tc * Dc * 2;
  unsigned short* ob  = (unsigned short*)p; p += (size_t)Tc * Dc * 2;
  unsigned short* big = (unsigned short*)p; p += (size_t)Tc * DFFc * 2;
  unsigned short* wqb = (unsigned short*)p; p += (size_t)Lc * QKVW * Dc * 2;
  unsigned short* wob = (unsigned short*)p; p += (size_t)Lc * Dc * Dc * 2;
  unsigned short* w1b = (unsigned short*)p; p += (size_t)Lc * DFFc * Dc * 2;
  unsigned short* w2b = (unsigned short*)p; p += (size_t)Lc * Dc * DFFc * 2;

  // merged weight conversion: 1 launch (x4 vectorized)
  const int nq = Lc * QKVW * Dc;
  const int no = Lc * Dc * Dc;
  const int n1 = Lc * DFFc * Dc;
  const int n2 = Lc * Dc * DFFc;
  const int ntot = nq + no + n1 + n2;
  k_f2bf4<<<ntot / 1024, 256, 0, stream>>>(Wqkv, Wo, W1, W2, wqb, wob, w1b, w2b,
                                           nq, nq + no, nq + no + n1, ntot);

  k_embed<<<(Tc * Dc) / 1024, 256, 0, stream>>>(x, W_in, b_in, pos, h, hb);

  for (int l = 0; l < Lc; ++l) {
    const unsigned short* wq_l = wqb + (size_t)l * QKVW * Dc;
    const unsigned short* wo_l = wob + (size_t)l * Dc * Dc;
    const unsigned short* w1_l = w1b + (size_t)l * DFFc * Dc;
    const unsigned short* w2_l = w2b + (size_t)l * Dc * DFFc;

    // qkv = hb @ Wqkv^T + bqkv  (bf16 out)
    k_mgemm<0, 1><<<dim3(QKVW / 128, Tc / 128), 256, 0, stream>>>(
        hb, wq_l, bqkv + (size_t)l * QKVW, big, Tc, QKVW, Dc);

    k_attn<<<Bc * Hc * (Sc / 64), 256, 0, stream>>>(big, ob);

    // t2 = ob @ Wo^T + bo  (fp32 raw; residual added in LN)
    k_mgemm<0, 0><<<dim3(Dc / 128, Tc / 128), 256, 0, stream>>>(
        ob, wo_l, bo + (size_t)l * Dc, t2, Tc, Dc, Dc);

    // h = LN1(h + t2); hb = bf16(h)
    k_lnr<<<Tc / 4, 256, 0, stream>>>(h, t2, ln1g + (size_t)l * Dc,
                                      ln1b + (size_t)l * Dc, hb);

    // big = gelu(hb @ W1^T + b1)  (bf16 out)
    k_mgemm<2, 1><<<dim3(DFFc / 128, Tc / 128), 256, 0, stream>>>(
        hb, w1_l, b1 + (size_t)l * DFFc, big, Tc, DFFc, Dc);

    // t2 = big @ W2^T + b2  (fp32 raw)
    k_mgemm<0, 0><<<dim3(Dc / 128, Tc / 128), 256, 0, stream>>>(
        big, w2_l, b2 + (size_t)l * Dc, t2, Tc, Dc, DFFc);

    // h = LN2(h + t2); hb = bf16(h)
    k_lnr<<<Tc / 4, 256, 0, stream>>>(h, t2, ln2g + (size_t)l * Dc,
                                      ln2b + (size_t)l * Dc, hb);
  }

  k_head<<<Tc / 4, 256, 0, stream>>>(h, Wh, bh, out);
}

// Round 15
// 562.171 us; speedup vs baseline: 1.0908x; 1.0213x over previous
//
#include <hip/hip_runtime.h>
#include <hip/hip_bf16.h>
#include <math.h>

// Problem constants
constexpr int Bc = 4;
constexpr int Sc = 2048;
constexpr int Dc = 512;
constexpr int Hc = 8;
constexpr int DHc = 64;
constexpr int Lc = 4;
constexpr int DFFc = 2048;
constexpr int Tc = Bc * Sc;   // 8192 tokens
constexpr int QKVW = 3 * Dc;  // 1536

typedef __attribute__((ext_vector_type(8))) short short8;
typedef __attribute__((ext_vector_type(4))) float f32x4;
typedef __attribute__((ext_vector_type(4))) float float4v;
typedef __attribute__((ext_vector_type(4))) unsigned int uint4v;
typedef __attribute__((ext_vector_type(2))) unsigned int uint2v;

static __device__ __forceinline__ float u16tof(unsigned int u) {
  return __uint_as_float(u << 16);
}
static __device__ __forceinline__ unsigned short ftobf(float f) {
  __hip_bfloat16 h = __float2bfloat16(f);
  return *reinterpret_cast<unsigned short*>(&h);
}
static __device__ __forceinline__ void gload_lds16(const void* g, void* l) {
  __builtin_amdgcn_global_load_lds(
      (const __attribute__((address_space(1))) void*)g,
      (__attribute__((address_space(3))) void*)l, 16, 0, 0);
}

// LDS chunk-swizzle helpers for attention (16B-chunk XOR, conflict-free b128)
static __device__ __forceinline__ int swzK(int row, int col) {  // width 64
  return row * 64 + ((((col >> 3) ^ (row & 7)) << 3) | (col & 7));
}
static __device__ __forceinline__ int swzW(int row, int col) {  // width 192
  return row * 192 + ((((col >> 3) ^ (row & 7)) << 3) | (col & 7));
}
// GEMM-family granule permutation
static __device__ __forceinline__ int gperm(int row, int ch) {
  return (row >> 1) * 8 + (((((row & 1) << 2) | ch)) ^ ((row >> 1) & 7));
}

// ---------------------------------------------------------------------------
// Merged fp32 -> bf16 weight conversion (all 4 tensors, one launch, x4 vec)
// ---------------------------------------------------------------------------
__global__ __launch_bounds__(256) void k_f2bf4(const float* __restrict__ p0,
                                               const float* __restrict__ p1,
                                               const float* __restrict__ p2,
                                               const float* __restrict__ p3,
                                               unsigned short* __restrict__ o0,
                                               unsigned short* __restrict__ o1,
                                               unsigned short* __restrict__ o2,
                                               unsigned short* __restrict__ o3,
                                               int n0, int n01, int n012, int n0123) {
  int i4 = (blockIdx.x * 256 + threadIdx.x) * 4;
  if (i4 >= n0123) return;
  const float* src;
  unsigned short* dst;
  int off;
  if (i4 < n0) { src = p0; dst = o0; off = i4; }
  else if (i4 < n01) { src = p1; dst = o1; off = i4 - n0; }
  else if (i4 < n012) { src = p2; dst = o2; off = i4 - n01; }
  else { src = p3; dst = o3; off = i4 - n012; }
  float4v v = *(const float4v*)&src[off];
  uint2v pk = {ftobf(v[0]) | ((unsigned int)ftobf(v[1]) << 16),
               ftobf(v[2]) | ((unsigned int)ftobf(v[3]) << 16)};
  *(uint2v*)&dst[off] = pk;
}

// ---------------------------------------------------------------------------
// Embed (vectorized x4): h = x @ W_in^T + b_in + pos ; also bf16 copy
// ---------------------------------------------------------------------------
__global__ __launch_bounds__(256) void k_embed(const float* __restrict__ x,
                                               const float* __restrict__ W_in,
                                               const float* __restrict__ b_in,
                                               const float* __restrict__ pos,
                                               float* __restrict__ h,
                                               unsigned short* __restrict__ hb) {
  int i4 = (blockIdx.x * 256 + threadIdx.x) * 4;
  int t = i4 >> 9;
  int d = i4 & 511;
  int s = t & (Sc - 1);
  float x0 = x[t * 2 + 0], x1 = x[t * 2 + 1];
  float4v w01 = *(const float4v*)&W_in[d * 2];
  float4v w23 = *(const float4v*)&W_in[d * 2 + 4];
  float4v pz = *(const float4v*)&pos[(size_t)s * Dc + d];
  float4v b4 = *(const float4v*)&b_in[d];
  float4v v;
  v[0] = x0 * w01[0] + x1 * w01[1] + b4[0] + pz[0];
  v[1] = x0 * w01[2] + x1 * w01[3] + b4[1] + pz[1];
  v[2] = x0 * w23[0] + x1 * w23[1] + b4[2] + pz[2];
  v[3] = x0 * w23[2] + x1 * w23[3] + b4[3] + pz[3];
  *(float4v*)&h[i4] = v;
  uint2v pk = {ftobf(v[0]) | ((unsigned int)ftobf(v[1]) << 16),
               ftobf(v[2]) | ((unsigned int)ftobf(v[3]) << 16)};
  *(uint2v*)&hb[i4] = pk;
}

// ---------------------------------------------------------------------------
// k_mgemm2 (r13 config): 128x128, BK=32, DOUBLE-buffer with per-step drain,
// 32 KB LDS, (256,4) -> ~40% occupancy. Best for LARGE-grid K=512 shapes
// (QKV grid 768, FF1 grid 1024) where occupancy is the dominant lever.
//   MODE 0: +bias ; MODE 2: +bias, exact GELU
//   OUTBF: 1 -> bf16 out, 0 -> fp32 out
// ---------------------------------------------------------------------------
template <int MODE, int OUTBF>
__global__ __launch_bounds__(256, 4) void k_mgemm2(const unsigned short* __restrict__ A,
                                                   const unsigned short* __restrict__ W,
                                                   const float* __restrict__ bias,
                                                   void* __restrict__ Cout,
                                                   int M, int N, int K) {
  __shared__ short SMEM[2][2][512 * 8];
  const int tid = threadIdx.x;
  const int lane = tid & 63;
  const int wid = tid >> 6;
  const int wm = wid >> 1;
  const int wn = wid & 1;

  const int nwg = gridDim.x * gridDim.y;
  const int bid = blockIdx.y * gridDim.x + blockIdx.x;
  const int swz = (bid & 7) * (nwg >> 3) + (bid >> 3);
  const int m0 = (swz / gridDim.x) * 128;
  const int n0 = (swz % gridDim.x) * 128;

  int r0S, c0S, r1S, c1S;
  {
    int p = tid;
    int rp = p >> 3, q = (p & 7) ^ (rp & 7);
    r0S = (rp << 1) | (q >> 2);
    c0S = q & 3;
    p = tid + 256;
    rp = p >> 3;
    q = (p & 7) ^ (rp & 7);
    r1S = (rp << 1) | (q >> 2);
    c1S = q & 3;
  }
  const unsigned short* a0p = A + (size_t)(m0 + r0S) * K + c0S * 8;
  const unsigned short* a1p = A + (size_t)(m0 + r1S) * K + c1S * 8;
  const unsigned short* b0p = W + (size_t)(n0 + r0S) * K + c0S * 8;
  const unsigned short* b1p = W + (size_t)(n0 + r1S) * K + c1S * 8;
  const int d0 = (tid & ~63) * 8;
  const int d1 = ((tid + 256) & ~63) * 8;

  f32x4 acc[4][4] = {};
  const int lr = lane & 15;
  const int chr = lane >> 4;

  gload_lds16(a0p, &SMEM[0][0][d0]);
  gload_lds16(a1p, &SMEM[0][0][d1]);
  gload_lds16(b0p, &SMEM[1][0][d0]);
  gload_lds16(b1p, &SMEM[1][0][d1]);
  __syncthreads();

  const int nsteps = K >> 5;
  int buf = 0;
  for (int s = 0; s < nsteps; ++s) {
    if (s + 1 < nsteps) {
      const int ko = (s + 1) << 5;
      gload_lds16(a0p + ko, &SMEM[0][buf ^ 1][d0]);
      gload_lds16(a1p + ko, &SMEM[0][buf ^ 1][d1]);
      gload_lds16(b0p + ko, &SMEM[1][buf ^ 1][d0]);
      gload_lds16(b1p + ko, &SMEM[1][buf ^ 1][d1]);
    }
    short8 af[4], bfr[4];
#pragma unroll
    for (int mi = 0; mi < 4; ++mi)
      af[mi] = *(const short8*)&SMEM[0][buf][gperm(wm * 64 + mi * 16 + lr, chr) * 8];
#pragma unroll
    for (int ni = 0; ni < 4; ++ni)
      bfr[ni] = *(const short8*)&SMEM[1][buf][gperm(wn * 64 + ni * 16 + lr, chr) * 8];
#pragma unroll
    for (int mi = 0; mi < 4; ++mi)
#pragma unroll
      for (int ni = 0; ni < 4; ++ni)
        acc[mi][ni] = __builtin_amdgcn_mfma_f32_16x16x32_bf16(
            af[mi], bfr[ni], acc[mi][ni], 0, 0, 0);
    __syncthreads();
    buf ^= 1;
  }

  // LDS-transpose epilogue
  float* cw = (float*)&SMEM[0][0][0] + wid * (16 * 68);
  const int cj = lane & 15;
  const int rj4 = (lane >> 4) * 4;
  const int rrd = lane >> 3;
  const int crd = (lane & 7) * 8;
#pragma unroll
  for (int mi = 0; mi < 4; ++mi) {
#pragma unroll
    for (int ni = 0; ni < 4; ++ni) {
      float bn = bias[n0 + wn * 64 + ni * 16 + cj];
#pragma unroll
      for (int j = 0; j < 4; ++j) {
        float v = acc[mi][ni][j] + bn;
        if (MODE == 2) v = 0.5f * v * (1.0f + erff(v * 0.70710678118654752f));
        cw[(rj4 + j) * 68 + ni * 16 + cj] = v;
      }
    }
    __builtin_amdgcn_sched_barrier(0);
#pragma unroll
    for (int t = 0; t < 2; ++t) {
      int rl = t * 8 + rrd;
      float4v v0 = *(const float4v*)&cw[rl * 68 + crd];
      float4v v1 = *(const float4v*)&cw[rl * 68 + crd + 4];
      size_t gbase = (size_t)(m0 + wm * 64 + mi * 16 + rl) * N +
                     (n0 + wn * 64 + crd);
      if (OUTBF) {
        unsigned int w0 = ftobf(v0[0]) | ((unsigned int)ftobf(v0[1]) << 16);
        unsigned int w1 = ftobf(v0[2]) | ((unsigned int)ftobf(v0[3]) << 16);
        unsigned int w2 = ftobf(v1[0]) | ((unsigned int)ftobf(v1[1]) << 16);
        unsigned int w3 = ftobf(v1[2]) | ((unsigned int)ftobf(v1[3]) << 16);
        uint4v pk = {w0, w1, w2, w3};
        *(uint4v*)&((unsigned short*)Cout)[gbase] = pk;
      } else {
        *(float4v*)&((float*)Cout)[gbase] = v0;
        *(float4v*)&((float*)Cout)[gbase + 4] = v1;
      }
    }
    __builtin_amdgcn_sched_barrier(0);
  }
}

// ---------------------------------------------------------------------------
// k_mgemm3 (r14 config): 128x128, BK=32, TRIPLE-buffer counted-vmcnt
// no-drain pipeline, 48 KB LDS, (256,3). Best for SMALL-grid / long-K
// shapes (Wo grid 256, W2 grid 256 K=2048) where exposed latency dominates.
// ---------------------------------------------------------------------------
template <int MODE, int OUTBF>
__global__ __launch_bounds__(256, 3) void k_mgemm3(const unsigned short* __restrict__ A,
                                                   const unsigned short* __restrict__ W,
                                                   const float* __restrict__ bias,
                                                   void* __restrict__ Cout,
                                                   int M, int N, int K) {
  __shared__ short SMEM[3][2][512 * 8];  // 48 KB
  const int tid = threadIdx.x;
  const int lane = tid & 63;
  const int wid = tid >> 6;
  const int wm = wid >> 1;
  const int wn = wid & 1;

  const int nwg = gridDim.x * gridDim.y;
  const int bid = blockIdx.y * gridDim.x + blockIdx.x;
  const int swz = (bid & 7) * (nwg >> 3) + (bid >> 3);
  const int m0 = (swz / gridDim.x) * 128;
  const int n0 = (swz % gridDim.x) * 128;

  int r0S, c0S, r1S, c1S;
  {
    int p = tid;
    int rp = p >> 3, q = (p & 7) ^ (rp & 7);
    r0S = (rp << 1) | (q >> 2);
    c0S = q & 3;
    p = tid + 256;
    rp = p >> 3;
    q = (p & 7) ^ (rp & 7);
    r1S = (rp << 1) | (q >> 2);
    c1S = q & 3;
  }
  const unsigned short* a0p = A + (size_t)(m0 + r0S) * K + c0S * 8;
  const unsigned short* a1p = A + (size_t)(m0 + r1S) * K + c1S * 8;
  const unsigned short* b0p = W + (size_t)(n0 + r0S) * K + c0S * 8;
  const unsigned short* b1p = W + (size_t)(n0 + r1S) * K + c1S * 8;
  const int d0 = (tid & ~63) * 8;
  const int d1 = ((tid + 256) & ~63) * 8;

  f32x4 acc[4][4] = {};
  const int lr = lane & 15;
  const int chr = lane >> 4;

  // prologue: stage tiles 0 and 1
#pragma unroll
  for (int t = 0; t < 2; ++t) {
    const int ko = t << 5;
    gload_lds16(a0p + ko, &SMEM[t][0][d0]);
    gload_lds16(a1p + ko, &SMEM[t][0][d1]);
    gload_lds16(b0p + ko, &SMEM[t][1][d0]);
    gload_lds16(b1p + ko, &SMEM[t][1][d1]);
  }

  const int nsteps = K >> 5;
  for (int s = 0; s < nsteps; ++s) {
    if (s + 1 < nsteps)
      asm volatile("s_waitcnt vmcnt(4)" ::: "memory");
    else
      asm volatile("s_waitcnt vmcnt(0)" ::: "memory");
    __builtin_amdgcn_s_barrier();
    __builtin_amdgcn_sched_barrier(0);

    if (s + 2 < nsteps) {
      const int ko = (s + 2) << 5;
      const int nb = (s + 2) % 3;
      gload_lds16(a0p + ko, &SMEM[nb][0][d0]);
      gload_lds16(a1p + ko, &SMEM[nb][0][d1]);
      gload_lds16(b0p + ko, &SMEM[nb][1][d0]);
      gload_lds16(b1p + ko, &SMEM[nb][1][d1]);
    }

    const int buf = s % 3;
    short8 af[4], bfr[4];
#pragma unroll
    for (int mi = 0; mi < 4; ++mi)
      af[mi] = *(const short8*)&SMEM[buf][0][gperm(wm * 64 + mi * 16 + lr, chr) * 8];
#pragma unroll
    for (int ni = 0; ni < 4; ++ni)
      bfr[ni] = *(const short8*)&SMEM[buf][1][gperm(wn * 64 + ni * 16 + lr, chr) * 8];
    asm volatile("s_waitcnt lgkmcnt(0)" ::: "memory");
    __builtin_amdgcn_sched_barrier(0);
#pragma unroll
    for (int mi = 0; mi < 4; ++mi)
#pragma unroll
      for (int ni = 0; ni < 4; ++ni)
        acc[mi][ni] = __builtin_amdgcn_mfma_f32_16x16x32_bf16(
            af[mi], bfr[ni], acc[mi][ni], 0, 0, 0);
  }
  __syncthreads();

  // LDS-transpose epilogue
  float* cw = (float*)&SMEM[0][0][0] + wid * (16 * 68);
  const int cj = lane & 15;
  const int rj4 = (lane >> 4) * 4;
  const int rrd = lane >> 3;
  const int crd = (lane & 7) * 8;
#pragma unroll
  for (int mi = 0; mi < 4; ++mi) {
#pragma unroll
    for (int ni = 0; ni < 4; ++ni) {
      float bn = bias[n0 + wn * 64 + ni * 16 + cj];
#pragma unroll
      for (int j = 0; j < 4; ++j) {
        float v = acc[mi][ni][j] + bn;
        if (MODE == 2) v = 0.5f * v * (1.0f + erff(v * 0.70710678118654752f));
        cw[(rj4 + j) * 68 + ni * 16 + cj] = v;
      }
    }
    __builtin_amdgcn_sched_barrier(0);
#pragma unroll
    for (int t = 0; t < 2; ++t) {
      int rl = t * 8 + rrd;
      float4v v0 = *(const float4v*)&cw[rl * 68 + crd];
      float4v v1 = *(const float4v*)&cw[rl * 68 + crd + 4];
      size_t gbase = (size_t)(m0 + wm * 64 + mi * 16 + rl) * N +
                     (n0 + wn * 64 + crd);
      if (OUTBF) {
        unsigned int w0 = ftobf(v0[0]) | ((unsigned int)ftobf(v0[1]) << 16);
        unsigned int w1 = ftobf(v0[2]) | ((unsigned int)ftobf(v0[3]) << 16);
        unsigned int w2 = ftobf(v1[0]) | ((unsigned int)ftobf(v1[1]) << 16);
        unsigned int w3 = ftobf(v1[2]) | ((unsigned int)ftobf(v1[3]) << 16);
        uint4v pk = {w0, w1, w2, w3};
        *(uint4v*)&((unsigned short*)Cout)[gbase] = pk;
      } else {
        *(float4v*)&((float*)Cout)[gbase] = v0;
        *(float4v*)&((float*)Cout)[gbase + 4] = v1;
      }
    }
    __builtin_amdgcn_sched_barrier(0);
  }
}

// ---------------------------------------------------------------------------
// Windowed causal attention, MFMA. qkv bf16 [T][1536]. PV kb-range trimmed.
// LDS 48 KB (Ps aliases Ks), 3 blocks/CU.
// ---------------------------------------------------------------------------
__global__ __launch_bounds__(256, 3) void k_attn(const unsigned short* __restrict__ qkv,
                                                 unsigned short* __restrict__ o) {
  __shared__ unsigned short KPs[192 * 64];  // K rows, then reused as P
  __shared__ unsigned short Vt[64 * 192];

  const int tid = threadIdx.x;
  const int lane = tid & 63;
  const int w = tid >> 6;
  const int idx = blockIdx.x;
  const int qb = idx & 31;
  const int hh = (idx >> 5) & 7;
  const int b = idx >> 8;
  const int q0 = qb * 64;
  const int kstart = max(0, q0 - 128);
  const int nk = q0 + 64 - kstart;  // 64 (qb==0) or 192

  for (int c = tid; c < nk * 8; c += 256) {
    int j = c >> 3, ch = c & 7;
    short8 kv = *(const short8*)&qkv[(size_t)(b * Sc + kstart + j) * QKVW + Dc + hh * DHc + ch * 8];
    *(short8*)&KPs[swzK(j, ch * 8)] = kv;
  }
  for (int c = tid; c < (nk >> 1) * 8; c += 256) {
    int jp = c >> 3, ch = c & 7;
    int j = jp * 2;
    const unsigned short* base =
        &qkv[(size_t)(b * Sc + kstart + j) * QKVW + 2 * Dc + hh * DHc + ch * 8];
    short8 v0 = *(const short8*)base;
    short8 v1 = *(const short8*)(base + QKVW);
#pragma unroll
    for (int i = 0; i < 8; ++i) {
      unsigned int pk = (unsigned short)v0[i] | ((unsigned int)(unsigned short)v1[i] << 16);
      *(unsigned int*)&Vt[swzW(ch * 8 + i, j)] = pk;
    }
  }
  if (nk < 192) {  // qb==0: zero Vt cols [64,192) so P*garbage can't NaN
    for (int c = tid; c < 64 * 64; c += 256) {
      int d = c >> 6, jo = c & 63;
      *(unsigned int*)&Vt[swzW(d, 64 + jo * 2)] = 0;
    }
  }

  const int qg = q0 + w * 16 + (lane & 15);
  const int kg8 = (lane >> 4) * 8;
  const unsigned short* qp = &qkv[(size_t)(b * Sc + qg) * QKVW + hh * DHc + kg8];
  short8 bq0 = *(const short8*)qp;
  short8 bq1 = *(const short8*)(qp + 32);
  __syncthreads();

  const int jb = max(0, q0 + w * 16 - 128) - kstart;

  f32x4 sacc[9];
#pragma unroll
  for (int t = 0; t < 9; ++t) {
    int key = jb + t * 16 + (lane & 15);
    short8 a0 = *(const short8*)&KPs[swzK(key, kg8)];
    short8 a1 = *(const short8*)&KPs[swzK(key, 32 + kg8)];
    f32x4 z = {0.f, 0.f, 0.f, 0.f};
    z = __builtin_amdgcn_mfma_f32_16x16x32_bf16(a0, bq0, z, 0, 0, 0);
    sacc[t] = __builtin_amdgcn_mfma_f32_16x16x32_bf16(a1, bq1, z, 0, 0, 0);
  }

  const int rj = (lane >> 4) * 4;
  float mx = -1e30f;
#pragma unroll
  for (int t = 0; t < 9; ++t) {
#pragma unroll
    for (int j = 0; j < 4; ++j) {
      int kglob = kstart + jb + t * 16 + rj + j;
      bool valid = (kglob <= qg) && (kglob + 128 >= qg);
      float s = valid ? sacc[t][j] * 0.125f : -1e30f;
      sacc[t][j] = s;
      mx = fmaxf(mx, s);
    }
  }
  mx = fmaxf(mx, __shfl_xor(mx, 16));
  mx = fmaxf(mx, __shfl_xor(mx, 32));
  float sum = 0.f;
#pragma unroll
  for (int t = 0; t < 9; ++t)
#pragma unroll
    for (int j = 0; j < 4; ++j) {
      float e = __expf(sacc[t][j] - mx);
      sacc[t][j] = e;
      sum += e;
    }
  sum += __shfl_xor(sum, 16);
  sum += __shfl_xor(sum, 32);
  const float inv = 1.0f / sum;

  __syncthreads();

  const int prow = w * 16 + (lane & 15);
#pragma unroll
  for (int t = 0; t < 9; ++t) {
    int c0 = jb + t * 16 + rj;
    unsigned int p0 = ftobf(sacc[t][0] * inv) |
                      ((unsigned int)ftobf(sacc[t][1] * inv) << 16);
    unsigned int p1 = ftobf(sacc[t][2] * inv) |
                      ((unsigned int)ftobf(sacc[t][3] * inv) << 16);
    *(unsigned int*)&KPs[swzW(prow, c0)] = p0;
    *(unsigned int*)&KPs[swzW(prow, c0 + 2)] = p1;
  }
  {
    int g2 = (lane >> 4) * 2;
    for (int col = g2; col < jb; col += 8)
      *(unsigned int*)&KPs[swzW(prow, col)] = 0;
    for (int col = jb + 144 + g2; col < 192; col += 8)
      *(unsigned int*)&KPs[swzW(prow, col)] = 0;
  }
  const int kb0 = jb >> 5;
  const int kbend = min(6, (jb + 144 + 31) >> 5);
  f32x4 oacc[4] = {};
  for (int kb = kb0; kb < kbend; ++kb) {
    short8 pa = *(const short8*)&KPs[swzW(prow, kb * 32 + kg8)];
#pragma unroll
    for (int dt = 0; dt < 4; ++dt) {
      short8 vb = *(const short8*)&Vt[swzW(dt * 16 + (lane & 15), kb * 32 + kg8)];
      oacc[dt] = __builtin_amdgcn_mfma_f32_16x16x32_bf16(pa, vb, oacc[dt], 0, 0, 0);
    }
  }
  const int cj = lane & 15;
#pragma unroll
  for (int j = 0; j < 4; ++j)
#pragma unroll
    for (int dt = 0; dt < 4; ++dt)
      o[(size_t)(b * Sc + q0 + w * 16 + rj + j) * Dc + hh * DHc + dt * 16 + cj] =
          ftobf(oacc[dt][j]);
}

// ---------------------------------------------------------------------------
// Residual + LayerNorm: h = LN(h + raw) over D=512; writes h fp32 + hb bf16.
// ---------------------------------------------------------------------------
__global__ __launch_bounds__(256) void k_lnr(float* __restrict__ h,
                                             const float* __restrict__ raw,
                                             const float* __restrict__ g,
                                             const float* __restrict__ bta,
                                             unsigned short* __restrict__ outb) {
  const int wid = threadIdx.x >> 6;
  const int lane = threadIdx.x & 63;
  const int t = blockIdx.x * 4 + wid;
  const float4v* hrow = (const float4v*)(h + (size_t)t * Dc);
  const float4v* rrow = (const float4v*)(raw + (size_t)t * Dc);
  float4v v[2];
  float sum = 0.0f, sq = 0.0f;
#pragma unroll
  for (int i = 0; i < 2; ++i) {
    float4v hv = hrow[lane + i * 64];
    float4v rv = rrow[lane + i * 64];
#pragma unroll
    for (int c = 0; c < 4; ++c) {
      float xv = rv[c] + hv[c];
      v[i][c] = xv;
      sum += xv;
      sq += xv * xv;
    }
  }
#pragma unroll
  for (int off = 32; off; off >>= 1) {
    sum += __shfl_xor(sum, off);
    sq += __shfl_xor(sq, off);
  }
  float m = sum * (1.0f / 512.0f);
  float var = sq * (1.0f / 512.0f) - m * m;
  float rstd = rsqrtf(var + 1e-5f);
  float4v* orow = (float4v*)(h + (size_t)t * Dc);
  unsigned int* brow = (unsigned int*)(outb + (size_t)t * Dc);
#pragma unroll
  for (int i = 0; i < 2; ++i) {
    int d4 = (lane + i * 64) * 4;
    float4v ov;
#pragma unroll
    for (int c = 0; c < 4; ++c)
      ov[c] = (v[i][c] - m) * rstd * g[d4 + c] + bta[d4 + c];
    orow[lane + i * 64] = ov;
    unsigned int p0 = ftobf(ov[0]) | ((unsigned int)ftobf(ov[1]) << 16);
    unsigned int p1 = ftobf(ov[2]) | ((unsigned int)ftobf(ov[3]) << 16);
    brow[(lane + i * 64) * 2] = p0;
    brow[(lane + i * 64) * 2 + 1] = p1;
  }
}

// ---------------------------------------------------------------------------
// Head (fp32): mu | clipped log_sigma
// ---------------------------------------------------------------------------
__global__ __launch_bounds__(256) void k_head(const float* __restrict__ h,
                                              const float* __restrict__ Wh,
                                              const float* __restrict__ bh,
                                              float* __restrict__ outp) {
  const int wid = threadIdx.x >> 6;
  const int lane = threadIdx.x & 63;
  const int t = blockIdx.x * 4 + wid;
  const float* row = h + (size_t)t * Dc;
  float a0 = 0, a1 = 0, a2 = 0, a3 = 0;
#pragma unroll
  for (int i = 0; i < 8; ++i) {
    int d = lane + i * 64;
    float xv = row[d];
    a0 += xv * Wh[0 * Dc + d];
    a1 += xv * Wh[1 * Dc + d];
    a2 += xv * Wh[2 * Dc + d];
    a3 += xv * Wh[3 * Dc + d];
  }
#pragma unroll
  for (int off = 32; off; off >>= 1) {
    a0 += __shfl_xor(a0, off);
    a1 += __shfl_xor(a1, off);
    a2 += __shfl_xor(a2, off);
    a3 += __shfl_xor(a3, off);
  }
  if (lane == 0) {
    outp[(size_t)t * 2 + 0] = a0 + bh[0];
    outp[(size_t)t * 2 + 1] = a1 + bh[1];
    outp[(size_t)Tc * 2 + (size_t)t * 2 + 0] = fminf(fmaxf(a2 + bh[2], -6.0f), 1.5f);
    outp[(size_t)Tc * 2 + (size_t)t * 2 + 1] = fminf(fmaxf(a3 + bh[3], -6.0f), 1.5f);
  }
}

// ---------------------------------------------------------------------------
extern "C" void kernel_launch(void* const* d_in, const int* in_sizes, int n_in,
                              void* d_out, int out_size, void* d_ws, size_t ws_size,
                              hipStream_t stream) {
  const float* x    = (const float*)d_in[0];
  const float* W_in = (const float*)d_in[1];
  const float* b_in = (const float*)d_in[2];
  const float* pos  = (const float*)d_in[3];
  const float* Wqkv = (const float*)d_in[4];
  const float* bqkv = (const float*)d_in[5];
  const float* Wo   = (const float*)d_in[6];
  const float* bo   = (const float*)d_in[7];
  const float* W1   = (const float*)d_in[8];
  const float* b1   = (const float*)d_in[9];
  const float* W2   = (const float*)d_in[10];
  const float* b2   = (const float*)d_in[11];
  const float* ln1g = (const float*)d_in[12];
  const float* ln1b = (const float*)d_in[13];
  const float* ln2g = (const float*)d_in[14];
  const float* ln2b = (const float*)d_in[15];
  const float* Wh   = (const float*)d_in[16];
  const float* bh   = (const float*)d_in[17];
  float* out = (float*)d_out;

  char* p = (char*)d_ws;
  float* h   = (float*)p;          p += (size_t)Tc * Dc * 4;   // residual stream fp32
  float* t2  = (float*)p;          p += (size_t)Tc * Dc * 4;   // raw GEMM out fp32
  unsigned short* hb  = (unsigned short*)p; p += (size_t)Tc * Dc * 2;
  unsigned short* ob  = (unsigned short*)p; p += (size_t)Tc * Dc * 2;
  unsigned short* big = (unsigned short*)p; p += (size_t)Tc * DFFc * 2;
  unsigned short* wqb = (unsigned short*)p; p += (size_t)Lc * QKVW * Dc * 2;
  unsigned short* wob = (unsigned short*)p; p += (size_t)Lc * Dc * Dc * 2;
  unsigned short* w1b = (unsigned short*)p; p += (size_t)Lc * DFFc * Dc * 2;
  unsigned short* w2b = (unsigned short*)p; p += (size_t)Lc * Dc * DFFc * 2;

  const int nq = Lc * QKVW * Dc;
  const int no = Lc * Dc * Dc;
  const int n1 = Lc * DFFc * Dc;
  const int n2 = Lc * Dc * DFFc;
  const int ntot = nq + no + n1 + n2;
  k_f2bf4<<<ntot / 1024, 256, 0, stream>>>(Wqkv, Wo, W1, W2, wqb, wob, w1b, w2b,
                                           nq, nq + no, nq + no + n1, ntot);

  k_embed<<<(Tc * Dc) / 1024, 256, 0, stream>>>(x, W_in, b_in, pos, h, hb);

  for (int l = 0; l < Lc; ++l) {
    const unsigned short* wq_l = wqb + (size_t)l * QKVW * Dc;
    const unsigned short* wo_l = wob + (size_t)l * Dc * Dc;
    const unsigned short* w1_l = w1b + (size_t)l * DFFc * Dc;
    const unsigned short* w2_l = w2b + (size_t)l * Dc * DFFc;

    // qkv = hb @ Wqkv^T + bqkv  (bf16 out) -- large grid, K=512: 2-buf/occ
    k_mgemm2<0, 1><<<dim3(QKVW / 128, Tc / 128), 256, 0, stream>>>(
        hb, wq_l, bqkv + (size_t)l * QKVW, big, Tc, QKVW, Dc);

    k_attn<<<Bc * Hc * (Sc / 64), 256, 0, stream>>>(big, ob);

    // t2 = ob @ Wo^T + bo  (fp32 raw) -- small grid: 3-buf no-drain
    k_mgemm3<0, 0><<<dim3(Dc / 128, Tc / 128), 256, 0, stream>>>(
        ob, wo_l, bo + (size_t)l * Dc, t2, Tc, Dc, Dc);

    // h = LN1(h + t2); hb = bf16(h)
    k_lnr<<<Tc / 4, 256, 0, stream>>>(h, t2, ln1g + (size_t)l * Dc,
                                      ln1b + (size_t)l * Dc, hb);

    // big = gelu(hb @ W1^T + b1)  (bf16 out) -- large grid, K=512: 2-buf/occ
    k_mgemm2<2, 1><<<dim3(DFFc / 128, Tc / 128), 256, 0, stream>>>(
        hb, w1_l, b1 + (size_t)l * DFFc, big, Tc, DFFc, Dc);

    // t2 = big @ W2^T + b2  (fp32 raw) -- small grid, K=2048: 3-buf no-drain
    k_mgemm3<0, 0><<<dim3(Dc / 128, Tc / 128), 256, 0, stream>>>(
        big, w2_l, b2 + (size_t)l * Dc, t2, Tc, Dc, DFFc);

    // h = LN2(h + t2); hb = bf16(h)
    k_lnr<<<Tc / 4, 256, 0, stream>>>(h, t2, ln2g + (size_t)l * Dc,
                                      ln2b + (size_t)l * Dc, hb);
  }

  k_head<<<Tc / 4, 256, 0, stream>>>(h, Wh, bh, out);
}

// Round 16
// 558.281 us; speedup vs baseline: 1.0984x; 1.0070x over previous
//
#include <hip/hip_runtime.h>
#include <hip/hip_bf16.h>
#include <math.h>

// Problem constants
constexpr int Bc = 4;
constexpr int Sc = 2048;
constexpr int Dc = 512;
constexpr int Hc = 8;
constexpr int DHc = 64;
constexpr int Lc = 4;
constexpr int DFFc = 2048;
constexpr int Tc = Bc * Sc;   // 8192 tokens
constexpr int QKVW = 3 * Dc;  // 1536

typedef __attribute__((ext_vector_type(8))) short short8;
typedef __attribute__((ext_vector_type(4))) float f32x4;
typedef __attribute__((ext_vector_type(4))) float float4v;
typedef __attribute__((ext_vector_type(4))) unsigned int uint4v;
typedef __attribute__((ext_vector_type(2))) unsigned int uint2v;

static __device__ __forceinline__ float u16tof(unsigned int u) {
  return __uint_as_float(u << 16);
}
static __device__ __forceinline__ unsigned short ftobf(float f) {
  __hip_bfloat16 h = __float2bfloat16(f);
  return *reinterpret_cast<unsigned short*>(&h);
}
static __device__ __forceinline__ void gload_lds16(const void* g, void* l) {
  __builtin_amdgcn_global_load_lds(
      (const __attribute__((address_space(1))) void*)g,
      (__attribute__((address_space(3))) void*)l, 16, 0, 0);
}

// LDS chunk-swizzle helpers for attention (16B-chunk XOR, conflict-free b128)
static __device__ __forceinline__ int swzK(int row, int col) {  // width 64
  return row * 64 + ((((col >> 3) ^ (row & 7)) << 3) | (col & 7));
}
static __device__ __forceinline__ int swzW(int row, int col) {  // width 192
  return row * 192 + ((((col >> 3) ^ (row & 7)) << 3) | (col & 7));
}
// GEMM-family granule permutation
static __device__ __forceinline__ int gperm(int row, int ch) {
  return (row >> 1) * 8 + (((((row & 1) << 2) | ch)) ^ ((row >> 1) & 7));
}

// ---------------------------------------------------------------------------
// Merged fp32 -> bf16 weight conversion (all 4 tensors, one launch, x4 vec)
// ---------------------------------------------------------------------------
__global__ __launch_bounds__(256) void k_f2bf4(const float* __restrict__ p0,
                                               const float* __restrict__ p1,
                                               const float* __restrict__ p2,
                                               const float* __restrict__ p3,
                                               unsigned short* __restrict__ o0,
                                               unsigned short* __restrict__ o1,
                                               unsigned short* __restrict__ o2,
                                               unsigned short* __restrict__ o3,
                                               int n0, int n01, int n012, int n0123) {
  int i4 = (blockIdx.x * 256 + threadIdx.x) * 4;
  if (i4 >= n0123) return;
  const float* src;
  unsigned short* dst;
  int off;
  if (i4 < n0) { src = p0; dst = o0; off = i4; }
  else if (i4 < n01) { src = p1; dst = o1; off = i4 - n0; }
  else if (i4 < n012) { src = p2; dst = o2; off = i4 - n01; }
  else { src = p3; dst = o3; off = i4 - n012; }
  float4v v = *(const float4v*)&src[off];
  uint2v pk = {ftobf(v[0]) | ((unsigned int)ftobf(v[1]) << 16),
               ftobf(v[2]) | ((unsigned int)ftobf(v[3]) << 16)};
  *(uint2v*)&dst[off] = pk;
}

// ---------------------------------------------------------------------------
// Embed (vectorized x4): h = x @ W_in^T + b_in + pos ; also bf16 copy
// ---------------------------------------------------------------------------
__global__ __launch_bounds__(256) void k_embed(const float* __restrict__ x,
                                               const float* __restrict__ W_in,
                                               const float* __restrict__ b_in,
                                               const float* __restrict__ pos,
                                               float* __restrict__ h,
                                               unsigned short* __restrict__ hb) {
  int i4 = (blockIdx.x * 256 + threadIdx.x) * 4;
  int t = i4 >> 9;
  int d = i4 & 511;
  int s = t & (Sc - 1);
  float x0 = x[t * 2 + 0], x1 = x[t * 2 + 1];
  float4v w01 = *(const float4v*)&W_in[d * 2];
  float4v w23 = *(const float4v*)&W_in[d * 2 + 4];
  float4v pz = *(const float4v*)&pos[(size_t)s * Dc + d];
  float4v b4 = *(const float4v*)&b_in[d];
  float4v v;
  v[0] = x0 * w01[0] + x1 * w01[1] + b4[0] + pz[0];
  v[1] = x0 * w01[2] + x1 * w01[3] + b4[1] + pz[1];
  v[2] = x0 * w23[0] + x1 * w23[1] + b4[2] + pz[2];
  v[3] = x0 * w23[2] + x1 * w23[3] + b4[3] + pz[3];
  *(float4v*)&h[i4] = v;
  uint2v pk = {ftobf(v[0]) | ((unsigned int)ftobf(v[1]) << 16),
               ftobf(v[2]) | ((unsigned int)ftobf(v[3]) << 16)};
  *(uint2v*)&hb[i4] = pk;
}

// ---------------------------------------------------------------------------
// k_mgemm2: 128x128, BK=32, double-buffer with per-step drain, 32 KB LDS,
// (256,4) -> ~40% occupancy. For LARGE-grid K=512 shapes (QKV, FF1).
//   MODE 0: +bias ; MODE 2: +bias, exact GELU
//   OUTBF: 1 -> bf16 out, 0 -> fp32 out
// ---------------------------------------------------------------------------
template <int MODE, int OUTBF>
__global__ __launch_bounds__(256, 4) void k_mgemm2(const unsigned short* __restrict__ A,
                                                   const unsigned short* __restrict__ W,
                                                   const float* __restrict__ bias,
                                                   void* __restrict__ Cout,
                                                   int M, int N, int K) {
  __shared__ short SMEM[2][2][512 * 8];
  const int tid = threadIdx.x;
  const int lane = tid & 63;
  const int wid = tid >> 6;
  const int wm = wid >> 1;
  const int wn = wid & 1;

  const int nwg = gridDim.x * gridDim.y;
  const int bid = blockIdx.y * gridDim.x + blockIdx.x;
  const int swz = (bid & 7) * (nwg >> 3) + (bid >> 3);
  const int m0 = (swz / gridDim.x) * 128;
  const int n0 = (swz % gridDim.x) * 128;

  int r0S, c0S, r1S, c1S;
  {
    int p = tid;
    int rp = p >> 3, q = (p & 7) ^ (rp & 7);
    r0S = (rp << 1) | (q >> 2);
    c0S = q & 3;
    p = tid + 256;
    rp = p >> 3;
    q = (p & 7) ^ (rp & 7);
    r1S = (rp << 1) | (q >> 2);
    c1S = q & 3;
  }
  const unsigned short* a0p = A + (size_t)(m0 + r0S) * K + c0S * 8;
  const unsigned short* a1p = A + (size_t)(m0 + r1S) * K + c1S * 8;
  const unsigned short* b0p = W + (size_t)(n0 + r0S) * K + c0S * 8;
  const unsigned short* b1p = W + (size_t)(n0 + r1S) * K + c1S * 8;
  const int d0 = (tid & ~63) * 8;
  const int d1 = ((tid + 256) & ~63) * 8;

  f32x4 acc[4][4] = {};
  const int lr = lane & 15;
  const int chr = lane >> 4;

  gload_lds16(a0p, &SMEM[0][0][d0]);
  gload_lds16(a1p, &SMEM[0][0][d1]);
  gload_lds16(b0p, &SMEM[1][0][d0]);
  gload_lds16(b1p, &SMEM[1][0][d1]);
  __syncthreads();

  const int nsteps = K >> 5;
  int buf = 0;
  for (int s = 0; s < nsteps; ++s) {
    if (s + 1 < nsteps) {
      const int ko = (s + 1) << 5;
      gload_lds16(a0p + ko, &SMEM[0][buf ^ 1][d0]);
      gload_lds16(a1p + ko, &SMEM[0][buf ^ 1][d1]);
      gload_lds16(b0p + ko, &SMEM[1][buf ^ 1][d0]);
      gload_lds16(b1p + ko, &SMEM[1][buf ^ 1][d1]);
    }
    short8 af[4], bfr[4];
#pragma unroll
    for (int mi = 0; mi < 4; ++mi)
      af[mi] = *(const short8*)&SMEM[0][buf][gperm(wm * 64 + mi * 16 + lr, chr) * 8];
#pragma unroll
    for (int ni = 0; ni < 4; ++ni)
      bfr[ni] = *(const short8*)&SMEM[1][buf][gperm(wn * 64 + ni * 16 + lr, chr) * 8];
#pragma unroll
    for (int mi = 0; mi < 4; ++mi)
#pragma unroll
      for (int ni = 0; ni < 4; ++ni)
        acc[mi][ni] = __builtin_amdgcn_mfma_f32_16x16x32_bf16(
            af[mi], bfr[ni], acc[mi][ni], 0, 0, 0);
    __syncthreads();
    buf ^= 1;
  }

  // LDS-transpose epilogue
  float* cw = (float*)&SMEM[0][0][0] + wid * (16 * 68);
  const int cj = lane & 15;
  const int rj4 = (lane >> 4) * 4;
  const int rrd = lane >> 3;
  const int crd = (lane & 7) * 8;
#pragma unroll
  for (int mi = 0; mi < 4; ++mi) {
#pragma unroll
    for (int ni = 0; ni < 4; ++ni) {
      float bn = bias[n0 + wn * 64 + ni * 16 + cj];
#pragma unroll
      for (int j = 0; j < 4; ++j) {
        float v = acc[mi][ni][j] + bn;
        if (MODE == 2) v = 0.5f * v * (1.0f + erff(v * 0.70710678118654752f));
        cw[(rj4 + j) * 68 + ni * 16 + cj] = v;
      }
    }
    __builtin_amdgcn_sched_barrier(0);
#pragma unroll
    for (int t = 0; t < 2; ++t) {
      int rl = t * 8 + rrd;
      float4v v0 = *(const float4v*)&cw[rl * 68 + crd];
      float4v v1 = *(const float4v*)&cw[rl * 68 + crd + 4];
      size_t gbase = (size_t)(m0 + wm * 64 + mi * 16 + rl) * N +
                     (n0 + wn * 64 + crd);
      if (OUTBF) {
        unsigned int w0 = ftobf(v0[0]) | ((unsigned int)ftobf(v0[1]) << 16);
        unsigned int w1 = ftobf(v0[2]) | ((unsigned int)ftobf(v0[3]) << 16);
        unsigned int w2 = ftobf(v1[0]) | ((unsigned int)ftobf(v1[1]) << 16);
        unsigned int w3 = ftobf(v1[2]) | ((unsigned int)ftobf(v1[3]) << 16);
        uint4v pk = {w0, w1, w2, w3};
        *(uint4v*)&((unsigned short*)Cout)[gbase] = pk;
      } else {
        *(float4v*)&((float*)Cout)[gbase] = v0;
        *(float4v*)&((float*)Cout)[gbase + 4] = v1;
      }
    }
    __builtin_amdgcn_sched_barrier(0);
  }
}

// ---------------------------------------------------------------------------
// k_mgemm3: 128x128, BK=32, triple-buffer counted-vmcnt no-drain pipeline,
// 48 KB LDS, (256,3). For SMALL-grid / long-K shapes (Wo, W2).
// ---------------------------------------------------------------------------
template <int MODE, int OUTBF>
__global__ __launch_bounds__(256, 3) void k_mgemm3(const unsigned short* __restrict__ A,
                                                   const unsigned short* __restrict__ W,
                                                   const float* __restrict__ bias,
                                                   void* __restrict__ Cout,
                                                   int M, int N, int K) {
  __shared__ short SMEM[3][2][512 * 8];  // 48 KB
  const int tid = threadIdx.x;
  const int lane = tid & 63;
  const int wid = tid >> 6;
  const int wm = wid >> 1;
  const int wn = wid & 1;

  const int nwg = gridDim.x * gridDim.y;
  const int bid = blockIdx.y * gridDim.x + blockIdx.x;
  const int swz = (bid & 7) * (nwg >> 3) + (bid >> 3);
  const int m0 = (swz / gridDim.x) * 128;
  const int n0 = (swz % gridDim.x) * 128;

  int r0S, c0S, r1S, c1S;
  {
    int p = tid;
    int rp = p >> 3, q = (p & 7) ^ (rp & 7);
    r0S = (rp << 1) | (q >> 2);
    c0S = q & 3;
    p = tid + 256;
    rp = p >> 3;
    q = (p & 7) ^ (rp & 7);
    r1S = (rp << 1) | (q >> 2);
    c1S = q & 3;
  }
  const unsigned short* a0p = A + (size_t)(m0 + r0S) * K + c0S * 8;
  const unsigned short* a1p = A + (size_t)(m0 + r1S) * K + c1S * 8;
  const unsigned short* b0p = W + (size_t)(n0 + r0S) * K + c0S * 8;
  const unsigned short* b1p = W + (size_t)(n0 + r1S) * K + c1S * 8;
  const int d0 = (tid & ~63) * 8;
  const int d1 = ((tid + 256) & ~63) * 8;

  f32x4 acc[4][4] = {};
  const int lr = lane & 15;
  const int chr = lane >> 4;

#pragma unroll
  for (int t = 0; t < 2; ++t) {
    const int ko = t << 5;
    gload_lds16(a0p + ko, &SMEM[t][0][d0]);
    gload_lds16(a1p + ko, &SMEM[t][0][d1]);
    gload_lds16(b0p + ko, &SMEM[t][1][d0]);
    gload_lds16(b1p + ko, &SMEM[t][1][d1]);
  }

  const int nsteps = K >> 5;
  for (int s = 0; s < nsteps; ++s) {
    if (s + 1 < nsteps)
      asm volatile("s_waitcnt vmcnt(4)" ::: "memory");
    else
      asm volatile("s_waitcnt vmcnt(0)" ::: "memory");
    __builtin_amdgcn_s_barrier();
    __builtin_amdgcn_sched_barrier(0);

    if (s + 2 < nsteps) {
      const int ko = (s + 2) << 5;
      const int nb = (s + 2) % 3;
      gload_lds16(a0p + ko, &SMEM[nb][0][d0]);
      gload_lds16(a1p + ko, &SMEM[nb][0][d1]);
      gload_lds16(b0p + ko, &SMEM[nb][1][d0]);
      gload_lds16(b1p + ko, &SMEM[nb][1][d1]);
    }

    const int buf = s % 3;
    short8 af[4], bfr[4];
#pragma unroll
    for (int mi = 0; mi < 4; ++mi)
      af[mi] = *(const short8*)&SMEM[buf][0][gperm(wm * 64 + mi * 16 + lr, chr) * 8];
#pragma unroll
    for (int ni = 0; ni < 4; ++ni)
      bfr[ni] = *(const short8*)&SMEM[buf][1][gperm(wn * 64 + ni * 16 + lr, chr) * 8];
    asm volatile("s_waitcnt lgkmcnt(0)" ::: "memory");
    __builtin_amdgcn_sched_barrier(0);
#pragma unroll
    for (int mi = 0; mi < 4; ++mi)
#pragma unroll
      for (int ni = 0; ni < 4; ++ni)
        acc[mi][ni] = __builtin_amdgcn_mfma_f32_16x16x32_bf16(
            af[mi], bfr[ni], acc[mi][ni], 0, 0, 0);
  }
  __syncthreads();

  // LDS-transpose epilogue
  float* cw = (float*)&SMEM[0][0][0] + wid * (16 * 68);
  const int cj = lane & 15;
  const int rj4 = (lane >> 4) * 4;
  const int rrd = lane >> 3;
  const int crd = (lane & 7) * 8;
#pragma unroll
  for (int mi = 0; mi < 4; ++mi) {
#pragma unroll
    for (int ni = 0; ni < 4; ++ni) {
      float bn = bias[n0 + wn * 64 + ni * 16 + cj];
#pragma unroll
      for (int j = 0; j < 4; ++j) {
        float v = acc[mi][ni][j] + bn;
        if (MODE == 2) v = 0.5f * v * (1.0f + erff(v * 0.70710678118654752f));
        cw[(rj4 + j) * 68 + ni * 16 + cj] = v;
      }
    }
    __builtin_amdgcn_sched_barrier(0);
#pragma unroll
    for (int t = 0; t < 2; ++t) {
      int rl = t * 8 + rrd;
      float4v v0 = *(const float4v*)&cw[rl * 68 + crd];
      float4v v1 = *(const float4v*)&cw[rl * 68 + crd + 4];
      size_t gbase = (size_t)(m0 + wm * 64 + mi * 16 + rl) * N +
                     (n0 + wn * 64 + crd);
      if (OUTBF) {
        unsigned int w0 = ftobf(v0[0]) | ((unsigned int)ftobf(v0[1]) << 16);
        unsigned int w1 = ftobf(v0[2]) | ((unsigned int)ftobf(v0[3]) << 16);
        unsigned int w2 = ftobf(v1[0]) | ((unsigned int)ftobf(v1[1]) << 16);
        unsigned int w3 = ftobf(v1[2]) | ((unsigned int)ftobf(v1[3]) << 16);
        uint4v pk = {w0, w1, w2, w3};
        *(uint4v*)&((unsigned short*)Cout)[gbase] = pk;
      } else {
        *(float4v*)&((float*)Cout)[gbase] = v0;
        *(float4v*)&((float*)Cout)[gbase + 4] = v1;
      }
    }
    __builtin_amdgcn_sched_barrier(0);
  }
}

// ---------------------------------------------------------------------------
// Windowed causal attention, MFMA. qkv bf16 [T][1536]. PV kb-range trimmed.
// LDS 48 KB (Ps aliases Ks), 3 blocks/CU.
// K rows staged via global_load_lds (pre-swizzled source, linear LDS dest):
// slot s of row r holds source chunk s^(r&7), matching swzK reads exactly.
// ---------------------------------------------------------------------------
__global__ __launch_bounds__(256, 3) void k_attn(const unsigned short* __restrict__ qkv,
                                                 unsigned short* __restrict__ o) {
  __shared__ unsigned short KPs[192 * 64];  // K rows, then reused as P
  __shared__ unsigned short Vt[64 * 192];

  const int tid = threadIdx.x;
  const int lane = tid & 63;
  const int w = tid >> 6;
  const int idx = blockIdx.x;
  const int qb = idx & 31;
  const int hh = (idx >> 5) & 7;
  const int b = idx >> 8;
  const int q0 = qb * 64;
  const int kstart = max(0, q0 - 128);
  const int nk = q0 + 64 - kstart;  // 64 (qb==0) or 192

  // K staging: gload_lds, 64 granules (16B) per wave-instr, linear dest
  {
    const unsigned short* kbase = qkv + (size_t)(b * Sc + kstart) * QKVW + Dc + hh * DHc;
    const int ng = nk * 8;
    for (int c = tid; c < ng; c += 256) {
      int row = c >> 3, slot = c & 7;
      int sch = slot ^ (row & 7);
      gload_lds16(kbase + (size_t)row * QKVW + sch * 8,
                  (char*)KPs + (c & ~63) * 16);
    }
  }
  // V staged transposed (manual; transpose can't use gload_lds)
  for (int c = tid; c < (nk >> 1) * 8; c += 256) {
    int jp = c >> 3, ch = c & 7;
    int j = jp * 2;
    const unsigned short* base =
        &qkv[(size_t)(b * Sc + kstart + j) * QKVW + 2 * Dc + hh * DHc + ch * 8];
    short8 v0 = *(const short8*)base;
    short8 v1 = *(const short8*)(base + QKVW);
#pragma unroll
    for (int i = 0; i < 8; ++i) {
      unsigned int pk = (unsigned short)v0[i] | ((unsigned int)(unsigned short)v1[i] << 16);
      *(unsigned int*)&Vt[swzW(ch * 8 + i, j)] = pk;
    }
  }
  if (nk < 192) {  // qb==0: zero Vt cols [64,192) so P*garbage can't NaN
    for (int c = tid; c < 64 * 64; c += 256) {
      int d = c >> 6, jo = c & 63;
      *(unsigned int*)&Vt[swzW(d, 64 + jo * 2)] = 0;
    }
  }

  const int qg = q0 + w * 16 + (lane & 15);
  const int kg8 = (lane >> 4) * 8;
  const unsigned short* qp = &qkv[(size_t)(b * Sc + qg) * QKVW + hh * DHc + kg8];
  short8 bq0 = *(const short8*)qp;
  short8 bq1 = *(const short8*)(qp + 32);
  __syncthreads();  // drains vmcnt (gload_lds) + lgkm (ds_writes)

  const int jb = max(0, q0 + w * 16 - 128) - kstart;

  f32x4 sacc[9];
#pragma unroll
  for (int t = 0; t < 9; ++t) {
    int key = jb + t * 16 + (lane & 15);
    short8 a0 = *(const short8*)&KPs[swzK(key, kg8)];
    short8 a1 = *(const short8*)&KPs[swzK(key, 32 + kg8)];
    f32x4 z = {0.f, 0.f, 0.f, 0.f};
    z = __builtin_amdgcn_mfma_f32_16x16x32_bf16(a0, bq0, z, 0, 0, 0);
    sacc[t] = __builtin_amdgcn_mfma_f32_16x16x32_bf16(a1, bq1, z, 0, 0, 0);
  }

  const int rj = (lane >> 4) * 4;
  float mx = -1e30f;
#pragma unroll
  for (int t = 0; t < 9; ++t) {
#pragma unroll
    for (int j = 0; j < 4; ++j) {
      int kglob = kstart + jb + t * 16 + rj + j;
      bool valid = (kglob <= qg) && (kglob + 128 >= qg);
      float s = valid ? sacc[t][j] * 0.125f : -1e30f;
      sacc[t][j] = s;
      mx = fmaxf(mx, s);
    }
  }
  mx = fmaxf(mx, __shfl_xor(mx, 16));
  mx = fmaxf(mx, __shfl_xor(mx, 32));
  float sum = 0.f;
#pragma unroll
  for (int t = 0; t < 9; ++t)
#pragma unroll
    for (int j = 0; j < 4; ++j) {
      float e = __expf(sacc[t][j] - mx);
      sacc[t][j] = e;
      sum += e;
    }
  sum += __shfl_xor(sum, 16);
  sum += __shfl_xor(sum, 32);
  const float inv = 1.0f / sum;

  __syncthreads();  // all K reads complete; hand KPs over to P storage

  const int prow = w * 16 + (lane & 15);
#pragma unroll
  for (int t = 0; t < 9; ++t) {
    int c0 = jb + t * 16 + rj;
    unsigned int p0 = ftobf(sacc[t][0] * inv) |
                      ((unsigned int)ftobf(sacc[t][1] * inv) << 16);
    unsigned int p1 = ftobf(sacc[t][2] * inv) |
                      ((unsigned int)ftobf(sacc[t][3] * inv) << 16);
    *(unsigned int*)&KPs[swzW(prow, c0)] = p0;
    *(unsigned int*)&KPs[swzW(prow, c0 + 2)] = p1;
  }
  {
    int g2 = (lane >> 4) * 2;
    for (int col = g2; col < jb; col += 8)
      *(unsigned int*)&KPs[swzW(prow, col)] = 0;
    for (int col = jb + 144 + g2; col < 192; col += 8)
      *(unsigned int*)&KPs[swzW(prow, col)] = 0;
  }
  const int kb0 = jb >> 5;
  const int kbend = min(6, (jb + 144 + 31) >> 5);
  f32x4 oacc[4] = {};
  for (int kb = kb0; kb < kbend; ++kb) {
    short8 pa = *(const short8*)&KPs[swzW(prow, kb * 32 + kg8)];
#pragma unroll
    for (int dt = 0; dt < 4; ++dt) {
      short8 vb = *(const short8*)&Vt[swzW(dt * 16 + (lane & 15), kb * 32 + kg8)];
      oacc[dt] = __builtin_amdgcn_mfma_f32_16x16x32_bf16(pa, vb, oacc[dt], 0, 0, 0);
    }
  }
  const int cj = lane & 15;
#pragma unroll
  for (int j = 0; j < 4; ++j)
#pragma unroll
    for (int dt = 0; dt < 4; ++dt)
      o[(size_t)(b * Sc + q0 + w * 16 + rj + j) * Dc + hh * DHc + dt * 16 + cj] =
          ftobf(oacc[dt][j]);
}

// ---------------------------------------------------------------------------
// Residual + LayerNorm: h = LN(h + raw) over D=512; writes h fp32 + hb bf16.
// ---------------------------------------------------------------------------
__global__ __launch_bounds__(256) void k_lnr(float* __restrict__ h,
                                             const float* __restrict__ raw,
                                             const float* __restrict__ g,
                                             const float* __restrict__ bta,
                                             unsigned short* __restrict__ outb) {
  const int wid = threadIdx.x >> 6;
  const int lane = threadIdx.x & 63;
  const int t = blockIdx.x * 4 + wid;
  const float4v* hrow = (const float4v*)(h + (size_t)t * Dc);
  const float4v* rrow = (const float4v*)(raw + (size_t)t * Dc);
  float4v v[2];
  float sum = 0.0f, sq = 0.0f;
#pragma unroll
  for (int i = 0; i < 2; ++i) {
    float4v hv = hrow[lane + i * 64];
    float4v rv = rrow[lane + i * 64];
#pragma unroll
    for (int c = 0; c < 4; ++c) {
      float xv = rv[c] + hv[c];
      v[i][c] = xv;
      sum += xv;
      sq += xv * xv;
    }
  }
#pragma unroll
  for (int off = 32; off; off >>= 1) {
    sum += __shfl_xor(sum, off);
    sq += __shfl_xor(sq, off);
  }
  float m = sum * (1.0f / 512.0f);
  float var = sq * (1.0f / 512.0f) - m * m;
  float rstd = rsqrtf(var + 1e-5f);
  float4v* orow = (float4v*)(h + (size_t)t * Dc);
  unsigned int* brow = (unsigned int*)(outb + (size_t)t * Dc);
#pragma unroll
  for (int i = 0; i < 2; ++i) {
    int d4 = (lane + i * 64) * 4;
    float4v ov;
#pragma unroll
    for (int c = 0; c < 4; ++c)
      ov[c] = (v[i][c] - m) * rstd * g[d4 + c] + bta[d4 + c];
    orow[lane + i * 64] = ov;
    unsigned int p0 = ftobf(ov[0]) | ((unsigned int)ftobf(ov[1]) << 16);
    unsigned int p1 = ftobf(ov[2]) | ((unsigned int)ftobf(ov[3]) << 16);
    brow[(lane + i * 64) * 2] = p0;
    brow[(lane + i * 64) * 2 + 1] = p1;
  }
}

// ---------------------------------------------------------------------------
// Head (fp32, float4-vectorized): mu | clipped log_sigma
// ---------------------------------------------------------------------------
__global__ __launch_bounds__(256) void k_head(const float* __restrict__ h,
                                              const float* __restrict__ Wh,
                                              const float* __restrict__ bh,
                                              float* __restrict__ outp) {
  const int wid = threadIdx.x >> 6;
  const int lane = threadIdx.x & 63;
  const int t = blockIdx.x * 4 + wid;
  const float4v* row4 = (const float4v*)(h + (size_t)t * Dc);
  const float4v* w0r = (const float4v*)(Wh + 0 * Dc);
  const float4v* w1r = (const float4v*)(Wh + 1 * Dc);
  const float4v* w2r = (const float4v*)(Wh + 2 * Dc);
  const float4v* w3r = (const float4v*)(Wh + 3 * Dc);
  float a0 = 0, a1 = 0, a2 = 0, a3 = 0;
#pragma unroll
  for (int i = 0; i < 2; ++i) {
    int d4 = lane + i * 64;
    float4v xv = row4[d4];
    float4v v0 = w0r[d4];
    float4v v1 = w1r[d4];
    float4v v2 = w2r[d4];
    float4v v3 = w3r[d4];
#pragma unroll
    for (int c = 0; c < 4; ++c) {
      a0 += xv[c] * v0[c];
      a1 += xv[c] * v1[c];
      a2 += xv[c] * v2[c];
      a3 += xv[c] * v3[c];
    }
  }
#pragma unroll
  for (int off = 32; off; off >>= 1) {
    a0 += __shfl_xor(a0, off);
    a1 += __shfl_xor(a1, off);
    a2 += __shfl_xor(a2, off);
    a3 += __shfl_xor(a3, off);
  }
  if (lane == 0) {
    outp[(size_t)t * 2 + 0] = a0 + bh[0];
    outp[(size_t)t * 2 + 1] = a1 + bh[1];
    outp[(size_t)Tc * 2 + (size_t)t * 2 + 0] = fminf(fmaxf(a2 + bh[2], -6.0f), 1.5f);
    outp[(size_t)Tc * 2 + (size_t)t * 2 + 1] = fminf(fmaxf(a3 + bh[3], -6.0f), 1.5f);
  }
}

// ---------------------------------------------------------------------------
extern "C" void kernel_launch(void* const* d_in, const int* in_sizes, int n_in,
                              void* d_out, int out_size, void* d_ws, size_t ws_size,
                              hipStream_t stream) {
  const float* x    = (const float*)d_in[0];
  const float* W_in = (const float*)d_in[1];
  const float* b_in = (const float*)d_in[2];
  const float* pos  = (const float*)d_in[3];
  const float* Wqkv = (const float*)d_in[4];
  const float* bqkv = (const float*)d_in[5];
  const float* Wo   = (const float*)d_in[6];
  const float* bo   = (const float*)d_in[7];
  const float* W1   = (const float*)d_in[8];
  const float* b1   = (const float*)d_in[9];
  const float* W2   = (const float*)d_in[10];
  const float* b2   = (const float*)d_in[11];
  const float* ln1g = (const float*)d_in[12];
  const float* ln1b = (const float*)d_in[13];
  const float* ln2g = (const float*)d_in[14];
  const float* ln2b = (const float*)d_in[15];
  const float* Wh   = (const float*)d_in[16];
  const float* bh   = (const float*)d_in[17];
  float* out = (float*)d_out;

  char* p = (char*)d_ws;
  float* h   = (float*)p;          p += (size_t)Tc * Dc * 4;   // residual stream fp32
  float* t2  = (float*)p;          p += (size_t)Tc * Dc * 4;   // raw GEMM out fp32
  unsigned short* hb  = (unsigned short*)p; p += (size_t)Tc * Dc * 2;
  unsigned short* ob  = (unsigned short*)p; p += (size_t)Tc * Dc * 2;
  unsigned short* big = (unsigned short*)p; p += (size_t)Tc * DFFc * 2;
  unsigned short* wqb = (unsigned short*)p; p += (size_t)Lc * QKVW * Dc * 2;
  unsigned short* wob = (unsigned short*)p; p += (size_t)Lc * Dc * Dc * 2;
  unsigned short* w1b = (unsigned short*)p; p += (size_t)Lc * DFFc * Dc * 2;
  unsigned short* w2b = (unsigned short*)p; p += (size_t)Lc * Dc * DFFc * 2;

  const int nq = Lc * QKVW * Dc;
  const int no = Lc * Dc * Dc;
  const int n1 = Lc * DFFc * Dc;
  const int n2 = Lc * Dc * DFFc;
  const int ntot = nq + no + n1 + n2;
  k_f2bf4<<<ntot / 1024, 256, 0, stream>>>(Wqkv, Wo, W1, W2, wqb, wob, w1b, w2b,
                                           nq, nq + no, nq + no + n1, ntot);

  k_embed<<<(Tc * Dc) / 1024, 256, 0, stream>>>(x, W_in, b_in, pos, h, hb);

  for (int l = 0; l < Lc; ++l) {
    const unsigned short* wq_l = wqb + (size_t)l * QKVW * Dc;
    const unsigned short* wo_l = wob + (size_t)l * Dc * Dc;
    const unsigned short* w1_l = w1b + (size_t)l * DFFc * Dc;
    const unsigned short* w2_l = w2b + (size_t)l * Dc * DFFc;

    // qkv = hb @ Wqkv^T + bqkv  (bf16 out) -- large grid, K=512: 2-buf/occ
    k_mgemm2<0, 1><<<dim3(QKVW / 128, Tc / 128), 256, 0, stream>>>(
        hb, wq_l, bqkv + (size_t)l * QKVW, big, Tc, QKVW, Dc);

    k_attn<<<Bc * Hc * (Sc / 64), 256, 0, stream>>>(big, ob);

    // t2 = ob @ Wo^T + bo  (fp32 raw) -- small grid: 3-buf no-drain
    k_mgemm3<0, 0><<<dim3(Dc / 128, Tc / 128), 256, 0, stream>>>(
        ob, wo_l, bo + (size_t)l * Dc, t2, Tc, Dc, Dc);

    // h = LN1(h + t2); hb = bf16(h)
    k_lnr<<<Tc / 4, 256, 0, stream>>>(h, t2, ln1g + (size_t)l * Dc,
                                      ln1b + (size_t)l * Dc, hb);

    // big = gelu(hb @ W1^T + b1)  (bf16 out) -- large grid, K=512: 2-buf/occ
    k_mgemm2<2, 1><<<dim3(DFFc / 128, Tc / 128), 256, 0, stream>>>(
        hb, w1_l, b1 + (size_t)l * DFFc, big, Tc, DFFc, Dc);

    // t2 = big @ W2^T + b2  (fp32 raw) -- small grid, K=2048: 3-buf no-drain
    k_mgemm3<0, 0><<<dim3(Dc / 128, Tc / 128), 256, 0, stream>>>(
        big, w2_l, b2 + (size_t)l * Dc, t2, Tc, Dc, DFFc);

    // h = LN2(h + t2); hb = bf16(h)
    k_lnr<<<Tc / 4, 256, 0, stream>>>(h, t2, ln2g + (size_t)l * Dc,
                                      ln2b + (size_t)l * Dc, hb);
  }

  k_head<<<Tc / 4, 256, 0, stream>>>(h, Wh, bh, out);
}